// Round 10
// baseline (173.420 us; speedup 1.0000x reference)
//
#include <hip/hip_runtime.h>
#include <stdint.h>

// ---------------------------------------------------------------------------
// SingleHeadedAttention (Mega-style, laplacian attn fn, causal, T5 rel bias)
// B=4, S=2048, DIM=1024, DQK=128, DV=1024.  fp32 in/out, bf16 MFMA internals.
// R18: R17's launch-bounds bump was a no-op: grids (576/512) cap blocks/CU at
//   2.25/2.0 -- the GRID, not the bound, was binding. Fix = smaller tiles:
//   - qkv: M-tile 128->64 rows, grid 1152 (4.5 blk/CU). bx==0: acc[4][2]
//     (128 dqk x 64 seq); v: acc[2][4] (64 seq x 128 n). 24 stage-units/step.
//   - out: N-tile 128->64 cols, grid 1024 (4.0 blk/CU). acc[2][4]
//     (64 n x 128 i); XCD pinning kept (8 nx-blocks share one attn panel).
//   Operands all L2/L3-resident -> halved tile costs no HBM traffic.
//   sim/prep unchanged.
// R15 lesson: NO cross-block data deps in-launch. R14: LDS-staged bodies
//   (global_load_lds w=16, BK=64, 2-barrier loop). R13: XCD-pinned grids,
//   fused prep. R12: swapped operands epilogues. R11: sim triangle grid.
// R10: branchless erf; swapped QK^T.
//   TILED: element (row,k) of [R][K] at
//     ((row>>4)*(K>>5) + (k>>5))*512 + ((k>>3)&3)*128 + (row&15)*8 + (k&7).
// ---------------------------------------------------------------------------

#define B_   4
#define S_   2048
#define DIM_ 1024
#define DQK  128
#define DV   1024
#define NQV  1152

typedef __attribute__((ext_vector_type(8))) short short8;   // 8 bf16
typedef __attribute__((ext_vector_type(4))) float f32x4;    // MFMA C/D

__device__ __forceinline__ uint16_t f32_to_bf16(float f) {
  uint32_t u = __float_as_uint(f);
  u += 0x7FFFu + ((u >> 16) & 1u);          // round-to-nearest-even
  return (uint16_t)(u >> 16);
}

__device__ __forceinline__ uint32_t pack_bf16(float a, float b) {
  return (uint32_t)f32_to_bf16(a) | ((uint32_t)f32_to_bf16(b) << 16);
}

__device__ __forceinline__ float silu_f(float x) {
  return x * __builtin_amdgcn_rcpf(1.0f + __expf(-x));
}

// 0.5*(1+erf((x-mu)/(std*sqrt2))), mu=sqrt(0.5), std=sqrt(pi/4).
// Branchless Abramowitz-Stegun 7.1.26 erf approx, |eps| <= 1.5e-7.
__device__ __forceinline__ float laplacian_attn(float x) {
  float z  = (x - 0.70710678118654752f) * 0.79788456080286536f;
  float az = fabsf(z);
  float t  = __builtin_amdgcn_rcpf(fmaf(0.3275911f, az, 1.0f));
  float w  = fmaf(1.061405429f, t, -1.453152027f);
  w = fmaf(w, t, 1.421413741f);
  w = fmaf(w, t, -0.284496736f);
  w = fmaf(w, t, 0.254829592f);
  float P  = w * t;
  float E  = __expf(-z * z);
  float ea = fmaf(-P, E, 1.0f);            // erf(|z|)
  float er = copysignf(ea, z);
  return fmaf(0.5f, er, 0.5f);
}

// global->LDS DMA, 16B per lane.
__device__ __forceinline__ void gload16(const uint16_t* g, uint16_t* l) {
  __builtin_amdgcn_global_load_lds(
      (const __attribute__((address_space(1))) void*)g,
      (__attribute__((address_space(3))) void*)l, 16, 0, 0);
}

// ---- wave-private MTxNT (16-row units) GEMM on TILED operands -------------
// (reg-direct; used by k_gemm_sim where K is tiny)
template <int MT, int NT, int DEPTH>
__device__ __forceinline__ void wave_gemm_t(
    const uint16_t* __restrict__ A, int KBa, int rbA,
    const uint16_t* __restrict__ Bt, int KBb, int rbB,
    int nkb, f32x4 acc[MT][NT])
{
  const int lane = threadIdx.x & 63;

  const uint16_t* pa[MT];
  const uint16_t* pb[NT];
  #pragma unroll
  for (int mt = 0; mt < MT; mt++)
    pa[mt] = A + (size_t)(rbA + mt) * KBa * 512 + lane * 8;
  #pragma unroll
  for (int nt = 0; nt < NT; nt++)
    pb[nt] = Bt + (size_t)(rbB + nt) * KBb * 512 + lane * 8;

  #pragma unroll
  for (int mt = 0; mt < MT; mt++)
    #pragma unroll
    for (int nt = 0; nt < NT; nt++) {
      f32x4 z = {0.0f, 0.0f, 0.0f, 0.0f};
      acc[mt][nt] = z;
    }

  short8 fa0[MT], fb0[NT], fa1[MT], fb1[NT];

  auto loads = [&](short8 fa[MT], short8 fb[NT], int kb) {
    #pragma unroll
    for (int mt = 0; mt < MT; mt++)
      fa[mt] = *(const short8*)(pa[mt] + (size_t)kb * 512);
    #pragma unroll
    for (int nt = 0; nt < NT; nt++)
      fb[nt] = *(const short8*)(pb[nt] + (size_t)kb * 512);
  };
  auto mfmas = [&](short8 fa[MT], short8 fb[NT]) {
    #pragma unroll
    for (int mt = 0; mt < MT; mt++)
      #pragma unroll
      for (int nt = 0; nt < NT; nt++)
        acc[mt][nt] = __builtin_amdgcn_mfma_f32_16x16x32_bf16(
            fa[mt], fb[nt], acc[mt][nt], 0, 0, 0);
  };

  if constexpr (DEPTH == 2) {
    loads(fa0, fb0, 0);
    loads(fa1, fb1, 1);
    for (int kb = 2; kb < nkb; kb += 2) {
      mfmas(fa0, fb0);
      loads(fa0, fb0, kb);
      mfmas(fa1, fb1);
      loads(fa1, fb1, kb + 1);
    }
    mfmas(fa0, fb0);
    mfmas(fa1, fb1);
  } else {
    short8 fa2[MT], fb2[NT], fa3[MT], fb3[NT];
    loads(fa0, fb0, 0);
    loads(fa1, fb1, 1);
    loads(fa2, fb2, 2);
    loads(fa3, fb3, 3);
    for (int kb = 4; kb < nkb; kb += 4) {
      mfmas(fa0, fb0);
      loads(fa0, fb0, kb);
      mfmas(fa1, fb1);
      loads(fa1, fb1, kb + 1);
      mfmas(fa2, fb2);
      loads(fa2, fb2, kb + 2);
      mfmas(fa3, fb3);
      loads(fa3, fb3, kb + 3);
    }
    mfmas(fa0, fb0);
    mfmas(fa1, fb1);
    mfmas(fa2, fb2);
    mfmas(fa3, fb3);
  }
}

// ---- fused prep kernel -----------------------------------------------------
__global__ __launch_bounds__(256) void k_prep(
    const float* __restrict__ x, const float* __restrict__ wqk,
    const float* __restrict__ wv, const float* __restrict__ rel,
    uint16_t* __restrict__ xb, uint16_t* __restrict__ wT,
    float* __restrict__ bias_n)
{
  int blk = blockIdx.x;
  if (blk < 4096) {
    int t = blk * 256 + threadIdx.x;           // 0 .. 8192*128-1
    int i16 = t & 15, oct = (t >> 4) & 3, kb = (t >> 6) & 31, ib = t >> 11;
    const float* src = x + (size_t)(ib * 16 + i16) * DIM_ + kb * 32 + oct * 8;
    float4 a = *(const float4*)src;
    float4 b = *(const float4*)(src + 4);
    short8 o;
    o[0] = f32_to_bf16(a.x); o[1] = f32_to_bf16(a.y);
    o[2] = f32_to_bf16(a.z); o[3] = f32_to_bf16(a.w);
    o[4] = f32_to_bf16(b.x); o[5] = f32_to_bf16(b.y);
    o[6] = f32_to_bf16(b.z); o[7] = f32_to_bf16(b.w);
    *(short8*)(xb + (size_t)t * 8) = o;
  } else if (blk < 4672) {
    int t = (blk - 4096) * 256 + threadIdx.x;  // 0 .. 1152*128-1
    int n16 = t & 15, oct = (t >> 4) & 3, kb = (t >> 6) & 31, nb = t >> 11;
    int n = nb * 16 + n16;
    int k0 = kb * 32 + oct * 8;
    short8 o;
    if (n < DQK) {
      #pragma unroll
      for (int j = 0; j < 8; j++)
        o[j] = f32_to_bf16(wqk[(size_t)(k0 + j) * DQK + n]);
    } else {
      int nn = n - DQK;
      #pragma unroll
      for (int j = 0; j < 8; j++)
        o[j] = f32_to_bf16(wv[(size_t)(k0 + j) * DV + nn]);
    }
    *(short8*)(wT + (size_t)t * 8) = o;
  } else {
    for (int n = threadIdx.x; n < S_; n += 256) {
      int bucket;
      if (n < 16) {
        bucket = n;
      } else {
        float tt = logf((float)n * 0.0625f) / 2.0794415416798357f * 16.0f;
        int vl = 16 + (int)tt;
        bucket = vl < 31 ? vl : 31;
      }
      bias_n[n] = rel[bucket] * 11.313708498984761f;
    }
  }
}

// ---- GEMM kernels ----------------------------------------------------------

// fused projections, LDS-staged, 64-row M-tiles. 1-D grid 1152, XCD-pinned
// (9 bx of a by on one XCD). by = 64-row xb panel (4 rb).
// bx==0: A=wT (8 rb dqk cols), B=xb (4 rb) -> acc[4][2], packed q/k stores.
// bx>=1: A=xb (4 rb), B=wT bx-panel (8 rb) -> acc[2][4], vT TILED stores.
__global__ __launch_bounds__(256, 4) void k_gemm_qkv(
    const uint16_t* __restrict__ xb, const uint16_t* __restrict__ wT,
    const float* __restrict__ bqk, const float* __restrict__ gamma,
    const float* __restrict__ beta, const float* __restrict__ bv,
    uint16_t* __restrict__ qb, uint16_t* __restrict__ kb,
    uint16_t* __restrict__ vT)
{
  int L = blockIdx.x;                    // 0..1151
  int c = L & 7;
  int idx = L >> 3;                      // 0..143
  int by = c + 8 * (idx / 9);            // 0..127 (64-row panel)
  int bx = idx % 9;
  int lane = threadIdx.x & 63;
  int wave = threadIdx.x >> 6;
  int lane16 = lane & 15;
  int quad = lane >> 4;

  __shared__ uint16_t sA[8 * 2 * 512];
  __shared__ uint16_t sB[8 * 2 * 512];

  const uint16_t* xpan = xb + (size_t)by * 4 * 32 * 512;

  if (bx == 0) {
    f32x4 acc[4][2];
    #pragma unroll
    for (int mt = 0; mt < 4; mt++)
      #pragma unroll
      for (int nt = 0; nt < 2; nt++) {
        f32x4 z = {0.0f, 0.0f, 0.0f, 0.0f};
        acc[mt][nt] = z;
      }

    for (int kbi = 0; kbi < 32; kbi += 2) {
      #pragma unroll
      for (int s = 0; s < 6; s++) {
        int u = wave * 6 + s;            // 0..23; A units 0..15, B 16..23
        if (u < 16) {
          int rb = u >> 1, kk = u & 1;
          gload16(wT + ((size_t)rb * 32 + kbi + kk) * 512 + lane * 8,
                  sA + (rb * 2 + kk) * 512);
        } else {
          int u2 = u - 16, rb = u2 >> 1, kk = u2 & 1;
          gload16(xpan + ((size_t)rb * 32 + kbi + kk) * 512 + lane * 8,
                  sB + (rb * 2 + kk) * 512);
        }
      }
      __syncthreads();
      #pragma unroll
      for (int kk = 0; kk < 2; kk++) {
        short8 fa[4], fb[2];
        #pragma unroll
        for (int mt = 0; mt < 4; mt++)
          fa[mt] = *(const short8*)(sA + (((wave >> 1) * 4 + mt) * 2 + kk) * 512 + lane * 8);
        #pragma unroll
        for (int nt = 0; nt < 2; nt++)
          fb[nt] = *(const short8*)(sB + (((wave & 1) * 2 + nt) * 2 + kk) * 512 + lane * 8);
        #pragma unroll
        for (int mt = 0; mt < 4; mt++)
          #pragma unroll
          for (int nt = 0; nt < 2; nt++)
            acc[mt][nt] = __builtin_amdgcn_mfma_f32_16x16x32_bf16(
                fa[mt], fb[nt], acc[mt][nt], 0, 0, 0);
      }
      __syncthreads();
    }

    int ibase = by * 64 + (wave & 1) * 32;
    int cbase = (wave >> 1) * 64;
    #pragma unroll
    for (int mt = 0; mt < 4; mt++) {
      int c0 = cbase + mt * 16 + quad * 4;
      float4 bb = *(const float4*)(bqk + c0);
      float4 g0 = *(const float4*)(gamma + c0);
      float4 g1 = *(const float4*)(gamma + DQK + c0);
      float4 e0 = *(const float4*)(beta + c0);
      float4 e1 = *(const float4*)(beta + DQK + c0);
      size_t coff = (size_t)(c0 >> 5) * 512 + ((c0 >> 3) & 3) * 128 + (c0 & 7);
      #pragma unroll
      for (int nt = 0; nt < 2; nt++) {
        int i = ibase + nt * 16 + lane16;
        float s0 = silu_f(acc[mt][nt][0] + bb.x);
        float s1 = silu_f(acc[mt][nt][1] + bb.y);
        float s2 = silu_f(acc[mt][nt][2] + bb.z);
        float s3 = silu_f(acc[mt][nt][3] + bb.w);
        uint2 pq, pk;
        pq.x = pack_bf16(fmaf(s0, g0.x, e0.x), fmaf(s1, g0.y, e0.y));
        pq.y = pack_bf16(fmaf(s2, g0.z, e0.z), fmaf(s3, g0.w, e0.w));
        pk.x = pack_bf16(fmaf(s0, g1.x, e1.x), fmaf(s1, g1.y, e1.y));
        pk.y = pack_bf16(fmaf(s2, g1.z, e1.z), fmaf(s3, g1.w, e1.w));
        size_t off = (size_t)(i >> 4) * 4 * 512 + (size_t)(i & 15) * 8 + coff;
        *(uint2*)(qb + off) = pq;
        *(uint2*)(kb + off) = pk;
      }
    }
  } else {
    const uint16_t* wpan = wT + (size_t)bx * 8 * 32 * 512;
    f32x4 acc[2][4];
    #pragma unroll
    for (int mt = 0; mt < 2; mt++)
      #pragma unroll
      for (int nt = 0; nt < 4; nt++) {
        f32x4 z = {0.0f, 0.0f, 0.0f, 0.0f};
        acc[mt][nt] = z;
      }

    for (int kbi = 0; kbi < 32; kbi += 2) {
      #pragma unroll
      for (int s = 0; s < 6; s++) {
        int u = wave * 6 + s;            // A units 0..7, B 8..23
        if (u < 8) {
          int rb = u >> 1, kk = u & 1;
          gload16(xpan + ((size_t)rb * 32 + kbi + kk) * 512 + lane * 8,
                  sA + (rb * 2 + kk) * 512);
        } else {
          int u2 = u - 8, rb = u2 >> 1, kk = u2 & 1;
          gload16(wpan + ((size_t)rb * 32 + kbi + kk) * 512 + lane * 8,
                  sB + (rb * 2 + kk) * 512);
        }
      }
      __syncthreads();
      #pragma unroll
      for (int kk = 0; kk < 2; kk++) {
        short8 fa[2], fb[4];
        #pragma unroll
        for (int mt = 0; mt < 2; mt++)
          fa[mt] = *(const short8*)(sA + (((wave >> 1) * 2 + mt) * 2 + kk) * 512 + lane * 8);
        #pragma unroll
        for (int nt = 0; nt < 4; nt++)
          fb[nt] = *(const short8*)(sB + (((wave & 1) * 4 + nt) * 2 + kk) * 512 + lane * 8);
        #pragma unroll
        for (int mt = 0; mt < 2; mt++)
          #pragma unroll
          for (int nt = 0; nt < 4; nt++)
            acc[mt][nt] = __builtin_amdgcn_mfma_f32_16x16x32_bf16(
                fa[mt], fb[nt], acc[mt][nt], 0, 0, 0);
      }
      __syncthreads();
    }

    int b = by >> 5;                     // batch (by*64 / 2048)
    uint16_t* vt = vT + (size_t)b * DV * S_;
    #pragma unroll
    for (int nt = 0; nt < 4; nt++) {
      int n = (bx - 1) * 128 + (wave & 1) * 64 + nt * 16 + lane16;  // 0..1023
      float bb = bv[n];
      #pragma unroll
      for (int mt = 0; mt < 2; mt++) {
        int j0l = (by & 31) * 64 + (wave >> 1) * 32 + mt * 16 + quad * 4;
        uint16_t v0 = f32_to_bf16(silu_f(acc[mt][nt][0] + bb));
        uint16_t v1 = f32_to_bf16(silu_f(acc[mt][nt][1] + bb));
        uint16_t v2 = f32_to_bf16(silu_f(acc[mt][nt][2] + bb));
        uint16_t v3 = f32_to_bf16(silu_f(acc[mt][nt][3] + bb));
        size_t off = (size_t)((n >> 4) * 64 + (j0l >> 5)) * 512 +
                     ((j0l >> 3) & 3) * 128 + (n & 15) * 8 + (j0l & 7);
        uint2 pk;
        pk.x = (uint32_t)v0 | ((uint32_t)v1 << 16);
        pk.y = (uint32_t)v2 | ((uint32_t)v3 << 16);
        *(uint2*)(vt + off) = pk;
      }
    }
  }
}

// attn = laplacian(q@k^T/S + bias[i-j]) causal, TILED bf16 per batch.
// 64x64 tile per 128-thread block (2 waves); exact causal triangle grid.
// SWAPPED: A = kb rows (j), B = qb rows (i). DEPTH4: single latency exposure.
__global__ __launch_bounds__(128, 6) void k_gemm_sim(
    const uint16_t* __restrict__ qb, const uint16_t* __restrict__ kb,
    const float* __restrict__ bias_n, uint16_t* __restrict__ attn)
{
  int b = blockIdx.x;                    // 0..527 triangular tile index
  int bt = blockIdx.y;                   // batch
  int it = (int)((sqrtf(8.0f * (float)b + 1.0f) - 1.0f) * 0.5f);
  while ((it + 1) * (it + 2) / 2 <= b) ++it;
  while (it * (it + 1) / 2 > b) --it;
  int jt = b - it * (it + 1) / 2;        // 0..it

  int lane = threadIdx.x & 63;
  int wave = threadIdx.x >> 6;           // 0..1 (i-halves of the 64-row tile)
  int lane16 = lane & 15;
  int quad = lane >> 4;

  f32x4 acc[4][2];
  wave_gemm_t<4,2,4>(kb, 4, bt * 128 + jt * 4,
                     qb, 4, bt * 128 + it * 4 + wave * 2,
                     4, acc);

  uint16_t* ab = attn + (size_t)bt * S_ * S_;
  int ibase = it * 64 + wave * 32;
  int jbase = jt * 64;
  #pragma unroll
  for (int nt = 0; nt < 2; nt++) {
    int i = ibase + nt * 16 + lane16;
    size_t irow = (size_t)(i >> 4) * 64 * 512 + (size_t)(i & 15) * 8;
    #pragma unroll
    for (int mt = 0; mt < 4; mt++) {
      int j0 = jbase + mt * 16 + quad * 4;
      float v[4];
      #pragma unroll
      for (int r = 0; r < 4; r++) {
        int j = j0 + r;
        float aval = 0.0f;
        if (j <= i) {
          float sim = acc[mt][nt][r] * (1.0f / 2048.0f) + bias_n[i - j];
          aval = laplacian_attn(sim);
        }
        v[r] = aval;
      }
      uint2 pk;
      pk.x = pack_bf16(v[0], v[1]);
      pk.y = pack_bf16(v[2], v[3]);
      size_t off = irow + (size_t)(j0 >> 5) * 512 + ((j0 >> 3) & 3) * 128 +
                   (j0 & 7);
      *(uint2*)(ab + off) = pk;
    }
  }
}

// out = attn @ v, fp32 out, LDS-staged, 64-col N-tiles. 1-D grid 1024:
// XCD c serves ONE bt (c>>1); nx = (c&1)*8 + (m&7) (0..15, 64-col vT panel,
// 4 rb); it = 15-(m>>3) (LPT desc). The 8 nx-blocks at same it on an XCD
// share one <=512KB attn panel in L2. A=vT (4 rb n), B=attn (8 rb i):
// acc[2][4]; float4 epilogue stores.
__global__ __launch_bounds__(256, 4) void k_gemm_out(
    const uint16_t* __restrict__ attn, const uint16_t* __restrict__ vT,
    float* __restrict__ out)
{
  int L = blockIdx.x;                    // 0..1023
  int c = L & 7, m = L >> 3;             // m: 0..127
  int bt = c >> 1;                       // one batch per XCD pair-residue
  int nx = (c & 1) * 8 + (m & 7);        // 0..15
  int it = 15 - (m >> 3);                // descending -> LPT
  int nkb = 4 * it + 4;                  // causal K bound (k-blocks, even)
  int lane = threadIdx.x & 63;
  int wave = threadIdx.x >> 6;
  int lane16 = lane & 15;
  int quad = lane >> 4;

  __shared__ uint16_t sA[4 * 2 * 512];   // vT panel: 4 rb
  __shared__ uint16_t sB[8 * 2 * 512];   // attn panel: 8 rb

  const uint16_t* Ab = vT + (size_t)bt * DV * S_ + (size_t)nx * 4 * 64 * 512;
  const uint16_t* Bb = attn + (size_t)bt * S_ * S_ + (size_t)it * 8 * 64 * 512;

  f32x4 acc[2][4];
  #pragma unroll
  for (int mt = 0; mt < 2; mt++)
    #pragma unroll
    for (int nt = 0; nt < 4; nt++) {
      f32x4 z = {0.0f, 0.0f, 0.0f, 0.0f};
      acc[mt][nt] = z;
    }

  for (int kbi = 0; kbi < nkb; kbi += 2) {
    #pragma unroll
    for (int s = 0; s < 6; s++) {
      int u = wave * 6 + s;              // A units 0..7, B 8..23
      if (u < 8) {
        int rb = u >> 1, kk = u & 1;
        gload16(Ab + ((size_t)rb * 64 + kbi + kk) * 512 + lane * 8,
                sA + (rb * 2 + kk) * 512);
      } else {
        int u2 = u - 8, rb = u2 >> 1, kk = u2 & 1;
        gload16(Bb + ((size_t)rb * 64 + kbi + kk) * 512 + lane * 8,
                sB + (rb * 2 + kk) * 512);
      }
    }
    __syncthreads();
    #pragma unroll
    for (int kk = 0; kk < 2; kk++) {
      short8 fa[2], fb[4];
      #pragma unroll
      for (int mt = 0; mt < 2; mt++)
        fa[mt] = *(const short8*)(sA + (((wave & 1) * 2 + mt) * 2 + kk) * 512 + lane * 8);
      #pragma unroll
      for (int nt = 0; nt < 4; nt++)
        fb[nt] = *(const short8*)(sB + (((wave >> 1) * 4 + nt) * 2 + kk) * 512 + lane * 8);
      #pragma unroll
      for (int mt = 0; mt < 2; mt++)
        #pragma unroll
        for (int nt = 0; nt < 4; nt++)
          acc[mt][nt] = __builtin_amdgcn_mfma_f32_16x16x32_bf16(
              fa[mt], fb[nt], acc[mt][nt], 0, 0, 0);
    }
    __syncthreads();
  }

  // acc[mt][nt][r]: n = nx*64 + (wave&1)*32 + mt*16 + quad*4 + r
  //                 i = it*128 + (wave>>1)*64 + nt*16 + lane16
  float* ob = out + ((size_t)bt * S_ + it * 128 + (wave >> 1) * 64) * DV +
              nx * 64 + (wave & 1) * 32;
  #pragma unroll
  for (int nt = 0; nt < 4; nt++) {
    int i = nt * 16 + lane16;
    #pragma unroll
    for (int mt = 0; mt < 2; mt++) {
      int n = mt * 16 + quad * 4;
      *(float4*)(ob + (size_t)i * DV + n) = *(float4*)&acc[mt][nt];
    }
  }
}

// ---------------------------------------------------------------------------

extern "C" void kernel_launch(void* const* d_in, const int* in_sizes, int n_in,
                              void* d_out, int out_size, void* d_ws, size_t ws_size,
                              hipStream_t stream)
{
  const float* x     = (const float*)d_in[0];
  const float* wqk   = (const float*)d_in[1];
  const float* bqk   = (const float*)d_in[2];
  const float* gamma = (const float*)d_in[3];
  const float* beta  = (const float*)d_in[4];
  const float* wv    = (const float*)d_in[5];
  const float* bv    = (const float*)d_in[6];
  const float* rel   = (const float*)d_in[7];
  float* out = (float*)d_out;

  char* ws = (char*)d_ws;
  size_t off = 0;
  uint16_t* xb     = (uint16_t*)(ws + off); off += (size_t)B_ * S_ * DIM_ * 2;  // 16 MB
  uint16_t* wT     = (uint16_t*)(ws + off); off += (size_t)NQV * DIM_ * 2;      // 2.25 MB
  uint16_t* qb     = (uint16_t*)(ws + off); off += (size_t)B_ * S_ * DQK * 2;   // 2 MB
  uint16_t* kb     = (uint16_t*)(ws + off); off += (size_t)B_ * S_ * DQK * 2;   // 2 MB
  uint16_t* vT     = (uint16_t*)(ws + off); off += (size_t)B_ * DV * S_ * 2;    // 16 MB
  uint16_t* attn   = (uint16_t*)(ws + off); off += (size_t)B_ * S_ * S_ * 2;    // 32 MB
  float*    bias_n = (float*)(ws + off);    off += (size_t)S_ * 4;              // 8 KB

  k_prep<<<dim3(4673), dim3(256), 0, stream>>>(x, wqk, wv, rel, xb, wT, bias_n);

  k_gemm_qkv<<<dim3(1152), dim3(256), 0, stream>>>(
      xb, wT, bqk, gamma, beta, bv, qb, kb, vT);
  k_gemm_sim<<<dim3(528, B_), dim3(128), 0, stream>>>(
      qb, kb, bias_n, attn);
  k_gemm_out<<<dim3(1024), dim3(256), 0, stream>>>(
      attn, vT, out);
}

// Round 12
// 169.046 us; speedup vs baseline: 1.0259x; 1.0259x over previous
//
#include <hip/hip_runtime.h>
#include <stdint.h>

// ---------------------------------------------------------------------------
// SingleHeadedAttention (Mega-style, laplacian attn fn, causal, T5 rel bias)
// B=4, S=2048, DIM=1024, DQK=128, DV=1024.  fp32 in/out, bf16 MFMA internals.
// R20: byte-equivalent resubmission of R19 (previous bench = container infra
//   failure, no measurement).
// R19: exact-R14 base (best measured, 171.0us) + T3 2-phase K-loop in
//   qkv/out: double-buffered LDS (BK 64->32, still 32KB total -> occupancy
//   unchanged), ONE barrier per K-step, stage(t+1) issued right after the
//   barrier so it overlaps compute(t). The old loop exposed full global->LDS
//   latency serially every step (stage->barrier->compute->barrier). R17/R18
//   proved TLP/tile-size are not the limiter; this attacks the vmcnt(0)
//   barrier drain (guide §5 m97-ceiling mechanism) instead.
// R15 lesson: NO cross-block data deps in-launch. R14: LDS-staged bodies
//   (global_load_lds w=16). R13: XCD-pinned grids, fused prep. R12: swapped
//   operand epilogues, LPT. R11: sim 32x64 wave tiles, triangle grid.
// R10: branchless erf; swapped QK^T.
//   TILED: element (row,k) of [R][K] at
//     ((row>>4)*(K>>5) + (k>>5))*512 + ((k>>3)&3)*128 + (row&15)*8 + (k&7).
// ---------------------------------------------------------------------------

#define B_   4
#define S_   2048
#define DIM_ 1024
#define DQK  128
#define DV   1024
#define NQV  1152

typedef __attribute__((ext_vector_type(8))) short short8;   // 8 bf16
typedef __attribute__((ext_vector_type(4))) float f32x4;    // MFMA C/D

__device__ __forceinline__ uint16_t f32_to_bf16(float f) {
  uint32_t u = __float_as_uint(f);
  u += 0x7FFFu + ((u >> 16) & 1u);          // round-to-nearest-even
  return (uint16_t)(u >> 16);
}

__device__ __forceinline__ uint32_t pack_bf16(float a, float b) {
  return (uint32_t)f32_to_bf16(a) | ((uint32_t)f32_to_bf16(b) << 16);
}

__device__ __forceinline__ float silu_f(float x) {
  return x * __builtin_amdgcn_rcpf(1.0f + __expf(-x));
}

// 0.5*(1+erf((x-mu)/(std*sqrt2))), mu=sqrt(0.5), std=sqrt(pi/4).
// Branchless Abramowitz-Stegun 7.1.26 erf approx, |eps| <= 1.5e-7.
__device__ __forceinline__ float laplacian_attn(float x) {
  float z  = (x - 0.70710678118654752f) * 0.79788456080286536f;
  float az = fabsf(z);
  float t  = __builtin_amdgcn_rcpf(fmaf(0.3275911f, az, 1.0f));
  float w  = fmaf(1.061405429f, t, -1.453152027f);
  w = fmaf(w, t, 1.421413741f);
  w = fmaf(w, t, -0.284496736f);
  w = fmaf(w, t, 0.254829592f);
  float P  = w * t;
  float E  = __expf(-z * z);
  float ea = fmaf(-P, E, 1.0f);            // erf(|z|)
  float er = copysignf(ea, z);
  return fmaf(0.5f, er, 0.5f);
}

// global->LDS DMA, 16B per lane.
__device__ __forceinline__ void gload16(const uint16_t* g, uint16_t* l) {
  __builtin_amdgcn_global_load_lds(
      (const __attribute__((address_space(1))) void*)g,
      (__attribute__((address_space(3))) void*)l, 16, 0, 0);
}

// ---- wave-private MTxNT (16-row units) GEMM on TILED operands -------------
// (reg-direct; used by k_gemm_sim where K is tiny)
template <int MT, int NT, int DEPTH>
__device__ __forceinline__ void wave_gemm_t(
    const uint16_t* __restrict__ A, int KBa, int rbA,
    const uint16_t* __restrict__ Bt, int KBb, int rbB,
    int nkb, f32x4 acc[MT][NT])
{
  const int lane = threadIdx.x & 63;

  const uint16_t* pa[MT];
  const uint16_t* pb[NT];
  #pragma unroll
  for (int mt = 0; mt < MT; mt++)
    pa[mt] = A + (size_t)(rbA + mt) * KBa * 512 + lane * 8;
  #pragma unroll
  for (int nt = 0; nt < NT; nt++)
    pb[nt] = Bt + (size_t)(rbB + nt) * KBb * 512 + lane * 8;

  #pragma unroll
  for (int mt = 0; mt < MT; mt++)
    #pragma unroll
    for (int nt = 0; nt < NT; nt++) {
      f32x4 z = {0.0f, 0.0f, 0.0f, 0.0f};
      acc[mt][nt] = z;
    }

  short8 fa0[MT], fb0[NT], fa1[MT], fb1[NT];

  auto loads = [&](short8 fa[MT], short8 fb[NT], int kb) {
    #pragma unroll
    for (int mt = 0; mt < MT; mt++)
      fa[mt] = *(const short8*)(pa[mt] + (size_t)kb * 512);
    #pragma unroll
    for (int nt = 0; nt < NT; nt++)
      fb[nt] = *(const short8*)(pb[nt] + (size_t)kb * 512);
  };
  auto mfmas = [&](short8 fa[MT], short8 fb[NT]) {
    #pragma unroll
    for (int mt = 0; mt < MT; mt++)
      #pragma unroll
      for (int nt = 0; nt < NT; nt++)
        acc[mt][nt] = __builtin_amdgcn_mfma_f32_16x16x32_bf16(
            fa[mt], fb[nt], acc[mt][nt], 0, 0, 0);
  };

  if constexpr (DEPTH == 2) {
    loads(fa0, fb0, 0);
    loads(fa1, fb1, 1);
    for (int kb = 2; kb < nkb; kb += 2) {
      mfmas(fa0, fb0);
      loads(fa0, fb0, kb);
      mfmas(fa1, fb1);
      loads(fa1, fb1, kb + 1);
    }
    mfmas(fa0, fb0);
    mfmas(fa1, fb1);
  } else {
    short8 fa2[MT], fb2[NT], fa3[MT], fb3[NT];
    loads(fa0, fb0, 0);
    loads(fa1, fb1, 1);
    loads(fa2, fb2, 2);
    loads(fa3, fb3, 3);
    for (int kb = 4; kb < nkb; kb += 4) {
      mfmas(fa0, fb0);
      loads(fa0, fb0, kb);
      mfmas(fa1, fb1);
      loads(fa1, fb1, kb + 1);
      mfmas(fa2, fb2);
      loads(fa2, fb2, kb + 2);
      mfmas(fa3, fb3);
      loads(fa3, fb3, kb + 3);
    }
    mfmas(fa0, fb0);
    mfmas(fa1, fb1);
    mfmas(fa2, fb2);
    mfmas(fa3, fb3);
  }
}

// ---- fused prep kernel -----------------------------------------------------
__global__ __launch_bounds__(256) void k_prep(
    const float* __restrict__ x, const float* __restrict__ wqk,
    const float* __restrict__ wv, const float* __restrict__ rel,
    uint16_t* __restrict__ xb, uint16_t* __restrict__ wT,
    float* __restrict__ bias_n)
{
  int blk = blockIdx.x;
  if (blk < 4096) {
    int t = blk * 256 + threadIdx.x;           // 0 .. 8192*128-1
    int i16 = t & 15, oct = (t >> 4) & 3, kb = (t >> 6) & 31, ib = t >> 11;
    const float* src = x + (size_t)(ib * 16 + i16) * DIM_ + kb * 32 + oct * 8;
    float4 a = *(const float4*)src;
    float4 b = *(const float4*)(src + 4);
    short8 o;
    o[0] = f32_to_bf16(a.x); o[1] = f32_to_bf16(a.y);
    o[2] = f32_to_bf16(a.z); o[3] = f32_to_bf16(a.w);
    o[4] = f32_to_bf16(b.x); o[5] = f32_to_bf16(b.y);
    o[6] = f32_to_bf16(b.z); o[7] = f32_to_bf16(b.w);
    *(short8*)(xb + (size_t)t * 8) = o;
  } else if (blk < 4672) {
    int t = (blk - 4096) * 256 + threadIdx.x;  // 0 .. 1152*128-1
    int n16 = t & 15, oct = (t >> 4) & 3, kb = (t >> 6) & 31, nb = t >> 11;
    int n = nb * 16 + n16;
    int k0 = kb * 32 + oct * 8;
    short8 o;
    if (n < DQK) {
      #pragma unroll
      for (int j = 0; j < 8; j++)
        o[j] = f32_to_bf16(wqk[(size_t)(k0 + j) * DQK + n]);
    } else {
      int nn = n - DQK;
      #pragma unroll
      for (int j = 0; j < 8; j++)
        o[j] = f32_to_bf16(wv[(size_t)(k0 + j) * DV + nn]);
    }
    *(short8*)(wT + (size_t)t * 8) = o;
  } else {
    for (int n = threadIdx.x; n < S_; n += 256) {
      int bucket;
      if (n < 16) {
        bucket = n;
      } else {
        float tt = logf((float)n * 0.0625f) / 2.0794415416798357f * 16.0f;
        int vl = 16 + (int)tt;
        bucket = vl < 31 ? vl : 31;
      }
      bias_n[n] = rel[bucket] * 11.313708498984761f;
    }
  }
}

// ---- GEMM kernels ----------------------------------------------------------

// fused projections, LDS-staged, 2-phase double-buffered (BK=32, 1 barrier
// per K-step, stage(t+1) overlaps compute(t)). 1-D grid 576, XCD-pinned.
// bx==0: q/k epilogue (SWAPPED operands -> packed 8B stores); bx>=1: v->vT.
__global__ __launch_bounds__(256, 3) void k_gemm_qkv(
    const uint16_t* __restrict__ xb, const uint16_t* __restrict__ wT,
    const float* __restrict__ bqk, const float* __restrict__ gamma,
    const float* __restrict__ beta, const float* __restrict__ bv,
    uint16_t* __restrict__ qb, uint16_t* __restrict__ kb,
    uint16_t* __restrict__ vT)
{
  int L = blockIdx.x;                    // 0..575
  int c = L & 7;
  int idx = L >> 3;                      // 0..71
  int by = c + 8 * (idx / 9);
  int bx = idx % 9;
  int lane = threadIdx.x & 63;
  int wave = threadIdx.x >> 6;
  int lane16 = lane & 15;
  int quad = lane >> 4;
  int wrow = (wave >> 1) * 64;
  int wcol = (wave & 1) * 64;

  __shared__ uint16_t sA[2][8 * 512];    // [buf][rbu*512]
  __shared__ uint16_t sB[2][8 * 512];

  const uint16_t *Ab, *Bb;
  if (bx == 0) { Ab = wT;                              Bb = xb + (size_t)by * 8 * 32 * 512; }
  else         { Ab = xb + (size_t)by * 8 * 32 * 512;  Bb = wT + (size_t)bx * 8 * 32 * 512; }

  const uint16_t* gp = (wave >> 1) ? Bb : Ab;
  int rb0 = (wave & 1) * 4;

  // wave stages rows rb0..rb0+3 of its panel for k-block kbi into buf b.
  auto stage = [&](int b, int kbi) {
    uint16_t* sp = (wave >> 1) ? sB[b] : sA[b];
    #pragma unroll
    for (int r = 0; r < 4; r++) {
      int rbu = rb0 + r;
      gload16(gp + ((size_t)rbu * 32 + kbi) * 512 + lane * 8,
              sp + rbu * 512);
    }
  };

  f32x4 acc[4][4];
  #pragma unroll
  for (int mt = 0; mt < 4; mt++)
    #pragma unroll
    for (int nt = 0; nt < 4; nt++) {
      f32x4 z = {0.0f, 0.0f, 0.0f, 0.0f};
      acc[mt][nt] = z;
    }

  stage(0, 0);
  int cur = 0;
  for (int kbi = 0; kbi < 32; ++kbi) {
    __syncthreads();                     // buf[cur] ready; prev reads done
    if (kbi + 1 < 32) stage(cur ^ 1, kbi + 1);   // overlaps compute below
    short8 fa[4], fb[4];
    #pragma unroll
    for (int mt = 0; mt < 4; mt++)
      fa[mt] = *(const short8*)(sA[cur] + ((wave >> 1) * 4 + mt) * 512 + lane * 8);
    #pragma unroll
    for (int nt = 0; nt < 4; nt++)
      fb[nt] = *(const short8*)(sB[cur] + ((wave & 1) * 4 + nt) * 512 + lane * 8);
    #pragma unroll
    for (int mt = 0; mt < 4; mt++)
      #pragma unroll
      for (int nt = 0; nt < 4; nt++)
        acc[mt][nt] = __builtin_amdgcn_mfma_f32_16x16x32_bf16(
            fa[mt], fb[nt], acc[mt][nt], 0, 0, 0);
    cur ^= 1;
  }

  if (bx == 0) {
    int ibase = by * 128 + (wave & 1) * 64;
    int cbase = (wave >> 1) * 64;
    #pragma unroll
    for (int mt = 0; mt < 4; mt++) {
      int c0 = cbase + mt * 16 + quad * 4;
      float4 bb = *(const float4*)(bqk + c0);
      float4 g0 = *(const float4*)(gamma + c0);
      float4 g1 = *(const float4*)(gamma + DQK + c0);
      float4 e0 = *(const float4*)(beta + c0);
      float4 e1 = *(const float4*)(beta + DQK + c0);
      size_t coff = (size_t)(c0 >> 5) * 512 + ((c0 >> 3) & 3) * 128 + (c0 & 7);
      #pragma unroll
      for (int nt = 0; nt < 4; nt++) {
        int i = ibase + nt * 16 + lane16;
        float s0 = silu_f(acc[mt][nt][0] + bb.x);
        float s1 = silu_f(acc[mt][nt][1] + bb.y);
        float s2 = silu_f(acc[mt][nt][2] + bb.z);
        float s3 = silu_f(acc[mt][nt][3] + bb.w);
        uint2 pq, pk;
        pq.x = pack_bf16(fmaf(s0, g0.x, e0.x), fmaf(s1, g0.y, e0.y));
        pq.y = pack_bf16(fmaf(s2, g0.z, e0.z), fmaf(s3, g0.w, e0.w));
        pk.x = pack_bf16(fmaf(s0, g1.x, e1.x), fmaf(s1, g1.y, e1.y));
        pk.y = pack_bf16(fmaf(s2, g1.z, e1.z), fmaf(s3, g1.w, e1.w));
        size_t off = (size_t)(i >> 4) * 4 * 512 + (size_t)(i & 15) * 8 + coff;
        *(uint2*)(qb + off) = pq;
        *(uint2*)(kb + off) = pk;
      }
    }
  } else {
    int b = by >> 4;                               // batch (by*128 / 2048)
    uint16_t* vt = vT + (size_t)b * DV * S_;
    #pragma unroll
    for (int nt = 0; nt < 4; nt++) {
      int n = (bx - 1) * 128 + wcol + nt * 16 + lane16;   // 0..1023
      float bb = bv[n];
      #pragma unroll
      for (int mt = 0; mt < 4; mt++) {
        int j0l = (by & 15) * 128 + wrow + mt * 16 + quad * 4; // local seq
        uint16_t v0 = f32_to_bf16(silu_f(acc[mt][nt][0] + bb));
        uint16_t v1 = f32_to_bf16(silu_f(acc[mt][nt][1] + bb));
        uint16_t v2 = f32_to_bf16(silu_f(acc[mt][nt][2] + bb));
        uint16_t v3 = f32_to_bf16(silu_f(acc[mt][nt][3] + bb));
        size_t off = (size_t)((n >> 4) * 64 + (j0l >> 5)) * 512 +
                     ((j0l >> 3) & 3) * 128 + (n & 15) * 8 + (j0l & 7);
        uint2 pk;
        pk.x = (uint32_t)v0 | ((uint32_t)v1 << 16);
        pk.y = (uint32_t)v2 | ((uint32_t)v3 << 16);
        *(uint2*)(vt + off) = pk;
      }
    }
  }
}

// attn = laplacian(q@k^T/S + bias[i-j]) causal, TILED bf16 per batch.
// 64x64 tile per 128-thread block (2 waves); exact causal triangle grid.
// SWAPPED: A = kb rows (j), B = qb rows (i).  (exact R14 config)
__global__ __launch_bounds__(128, 4) void k_gemm_sim(
    const uint16_t* __restrict__ qb, const uint16_t* __restrict__ kb,
    const float* __restrict__ bias_n, uint16_t* __restrict__ attn)
{
  int b = blockIdx.x;                    // 0..527 triangular tile index
  int bt = blockIdx.y;                   // batch
  int it = (int)((sqrtf(8.0f * (float)b + 1.0f) - 1.0f) * 0.5f);
  while ((it + 1) * (it + 2) / 2 <= b) ++it;
  while (it * (it + 1) / 2 > b) --it;
  int jt = b - it * (it + 1) / 2;        // 0..it

  int lane = threadIdx.x & 63;
  int wave = threadIdx.x >> 6;           // 0..1 (i-halves of the 64-row tile)
  int lane16 = lane & 15;
  int quad = lane >> 4;

  f32x4 acc[4][2];
  wave_gemm_t<4,2,2>(kb, 4, bt * 128 + jt * 4,
                     qb, 4, bt * 128 + it * 4 + wave * 2,
                     4, acc);

  uint16_t* ab = attn + (size_t)bt * S_ * S_;
  int ibase = it * 64 + wave * 32;
  int jbase = jt * 64;
  #pragma unroll
  for (int nt = 0; nt < 2; nt++) {
    int i = ibase + nt * 16 + lane16;
    size_t irow = (size_t)(i >> 4) * 64 * 512 + (size_t)(i & 15) * 8;
    #pragma unroll
    for (int mt = 0; mt < 4; mt++) {
      int j0 = jbase + mt * 16 + quad * 4;
      float v[4];
      #pragma unroll
      for (int r = 0; r < 4; r++) {
        int j = j0 + r;
        float aval = 0.0f;
        if (j <= i) {
          float sim = acc[mt][nt][r] * (1.0f / 2048.0f) + bias_n[i - j];
          aval = laplacian_attn(sim);
        }
        v[r] = aval;
      }
      uint2 pk;
      pk.x = pack_bf16(v[0], v[1]);
      pk.y = pack_bf16(v[2], v[3]);
      size_t off = irow + (size_t)(j0 >> 5) * 512 + ((j0 >> 3) & 3) * 128 +
                   (j0 & 7);
      *(uint2*)(ab + off) = pk;
    }
  }
}

// out = attn @ v, fp32 out, LDS-staged, 2-phase double-buffered (BK=32).
// 1-D grid 512: XCD c serves ONE bt (c>>1); nx=(c&1)*4+(m&3); it=15-(m>>2)
// (LPT desc). SWAPPED operands: A=vT (n rows, sA), B=attn (i rows, sB)
// -> float4 epilogue stores.
__global__ __launch_bounds__(256, 3) void k_gemm_out(
    const uint16_t* __restrict__ attn, const uint16_t* __restrict__ vT,
    float* __restrict__ out)
{
  int L = blockIdx.x;                    // 0..511
  int c = L & 7, m = L >> 3;             // c: XCD residue, m: 0..63
  int bt = c >> 1;                       // one batch per XCD pair-residue
  int nx = (c & 1) * 4 + (m & 3);        // 0..7
  int it = 15 - (m >> 2);                // descending -> LPT
  int nkb = 4 * it + 4;                  // causal K bound (32-wide k-blocks)
  int lane = threadIdx.x & 63;
  int wave = threadIdx.x >> 6;
  int lane16 = lane & 15;
  int quad = lane >> 4;
  int wrow = (wave >> 1) * 64;
  int wcol = (wave & 1) * 64;

  __shared__ uint16_t sA[2][8 * 512];
  __shared__ uint16_t sB[2][8 * 512];

  const uint16_t* Ab = vT + (size_t)bt * DV * S_ + (size_t)nx * 8 * 64 * 512;
  const uint16_t* Bb = attn + (size_t)bt * S_ * S_ + (size_t)it * 8 * 64 * 512;

  const uint16_t* gp = (wave >> 1) ? Bb : Ab;
  int rb0 = (wave & 1) * 4;

  auto stage = [&](int b, int kbi) {
    uint16_t* sp = (wave >> 1) ? sB[b] : sA[b];
    #pragma unroll
    for (int r = 0; r < 4; r++) {
      int rbu = rb0 + r;
      gload16(gp + ((size_t)rbu * 64 + kbi) * 512 + lane * 8,
              sp + rbu * 512);
    }
  };

  f32x4 acc[4][4];
  #pragma unroll
  for (int mt = 0; mt < 4; mt++)
    #pragma unroll
    for (int nt = 0; nt < 4; nt++) {
      f32x4 z = {0.0f, 0.0f, 0.0f, 0.0f};
      acc[mt][nt] = z;
    }

  stage(0, 0);
  int cur = 0;
  for (int kbi = 0; kbi < nkb; ++kbi) {
    __syncthreads();
    if (kbi + 1 < nkb) stage(cur ^ 1, kbi + 1);
    short8 fa[4], fb[4];
    #pragma unroll
    for (int mt = 0; mt < 4; mt++)
      fa[mt] = *(const short8*)(sA[cur] + ((wave & 1) * 4 + mt) * 512 + lane * 8);
    #pragma unroll
    for (int nt = 0; nt < 4; nt++)
      fb[nt] = *(const short8*)(sB[cur] + ((wave >> 1) * 4 + nt) * 512 + lane * 8);
    #pragma unroll
    for (int mt = 0; mt < 4; mt++)
      #pragma unroll
      for (int nt = 0; nt < 4; nt++)
        acc[mt][nt] = __builtin_amdgcn_mfma_f32_16x16x32_bf16(
            fa[mt], fb[nt], acc[mt][nt], 0, 0, 0);
    cur ^= 1;
  }

  // acc[mt][nt][r]: n = nx*128 + wcol + mt*16 + quad*4 + r
  //                 i = it*128 + wrow + nt*16 + lane16
  float* ob = out + ((size_t)bt * S_ + it * 128 + wrow) * DV + nx * 128 + wcol;
  #pragma unroll
  for (int nt = 0; nt < 4; nt++) {
    int i = nt * 16 + lane16;
    #pragma unroll
    for (int mt = 0; mt < 4; mt++) {
      int n = mt * 16 + quad * 4;
      *(float4*)(ob + (size_t)i * DV + n) = *(float4*)&acc[mt][nt];
    }
  }
}

// ---------------------------------------------------------------------------

extern "C" void kernel_launch(void* const* d_in, const int* in_sizes, int n_in,
                              void* d_out, int out_size, void* d_ws, size_t ws_size,
                              hipStream_t stream)
{
  const float* x     = (const float*)d_in[0];
  const float* wqk   = (const float*)d_in[1];
  const float* bqk   = (const float*)d_in[2];
  const float* gamma = (const float*)d_in[3];
  const float* beta  = (const float*)d_in[4];
  const float* wv    = (const float*)d_in[5];
  const float* bv    = (const float*)d_in[6];
  const float* rel   = (const float*)d_in[7];
  float* out = (float*)d_out;

  char* ws = (char*)d_ws;
  size_t off = 0;
  uint16_t* xb     = (uint16_t*)(ws + off); off += (size_t)B_ * S_ * DIM_ * 2;  // 16 MB
  uint16_t* wT     = (uint16_t*)(ws + off); off += (size_t)NQV * DIM_ * 2;      // 2.25 MB
  uint16_t* qb     = (uint16_t*)(ws + off); off += (size_t)B_ * S_ * DQK * 2;   // 2 MB
  uint16_t* kb     = (uint16_t*)(ws + off); off += (size_t)B_ * S_ * DQK * 2;   // 2 MB
  uint16_t* vT     = (uint16_t*)(ws + off); off += (size_t)B_ * DV * S_ * 2;    // 16 MB
  uint16_t* attn   = (uint16_t*)(ws + off); off += (size_t)B_ * S_ * S_ * 2;    // 32 MB
  float*    bias_n = (float*)(ws + off);    off += (size_t)S_ * 4;              // 8 KB

  k_prep<<<dim3(4673), dim3(256), 0, stream>>>(x, wqk, wv, rel, xb, wT, bias_n);

  k_gemm_qkv<<<dim3(576), dim3(256), 0, stream>>>(
      xb, wT, bqk, gamma, beta, bv, qb, kb, vT);
  k_gemm_sim<<<dim3(528, B_), dim3(128), 0, stream>>>(
      qb, kb, bias_n, attn);
  k_gemm_out<<<dim3(512), dim3(256), 0, stream>>>(
      attn, vT, out);
}

// Round 13
// 167.797 us; speedup vs baseline: 1.0335x; 1.0074x over previous
//
#include <hip/hip_runtime.h>
#include <stdint.h>

// ---------------------------------------------------------------------------
// SingleHeadedAttention (Mega-style, laplacian attn fn, causal, T5 rel bias)
// B=4, S=2048, DIM=1024, DQK=128, DV=1024.  fp32 in/out, bf16 MFMA internals.
// R21: R19/R20 (169.0us best) + depth-2 staging pipeline in qkv/out:
//   triple-buffered LDS (3x16KB=48KB, still 3 blk/CU), raw s_barrier with
//   counted `s_waitcnt vmcnt(4)` (each wave = 4 gload16/stage; waits for
//   stage t, leaves stage t+1 in flight ACROSS the barrier; stage t+2 issued
//   after). Every load gets 2 compute phases to land (plain __syncthreads
//   drains vmcnt(0) -> caps pipeline depth at 1; this lifts it).
//   Ledger: RAW = per-wave vmcnt(4) then barrier; WAR = buf (t+2)%3 last
//   read in compute(t-1), reads complete in-wave pre-barrier; last iter
//   vmcnt(0). Guards: "memory" clobber + sched_barrier(0) (guide rule 18).
// R19: 2-phase dbuf (BK=32, 1 barrier/step) -> 171->169. R15 lesson: NO
//   cross-block deps in-launch. R14: LDS-staged bodies (global_load_lds
//   w=16). R13: XCD-pinned grids, fused prep. R12: swapped epilogues, LPT.
// R11: sim 32x64 wave tiles, triangle grid. R10: branchless erf, swapped QKT.
//   TILED: element (row,k) of [R][K] at
//     ((row>>4)*(K>>5) + (k>>5))*512 + ((k>>3)&3)*128 + (row&15)*8 + (k&7).
// ---------------------------------------------------------------------------

#define B_   4
#define S_   2048
#define DIM_ 1024
#define DQK  128
#define DV   1024
#define NQV  1152

typedef __attribute__((ext_vector_type(8))) short short8;   // 8 bf16
typedef __attribute__((ext_vector_type(4))) float f32x4;    // MFMA C/D

__device__ __forceinline__ uint16_t f32_to_bf16(float f) {
  uint32_t u = __float_as_uint(f);
  u += 0x7FFFu + ((u >> 16) & 1u);          // round-to-nearest-even
  return (uint16_t)(u >> 16);
}

__device__ __forceinline__ uint32_t pack_bf16(float a, float b) {
  return (uint32_t)f32_to_bf16(a) | ((uint32_t)f32_to_bf16(b) << 16);
}

__device__ __forceinline__ float silu_f(float x) {
  return x * __builtin_amdgcn_rcpf(1.0f + __expf(-x));
}

// 0.5*(1+erf((x-mu)/(std*sqrt2))), mu=sqrt(0.5), std=sqrt(pi/4).
// Branchless Abramowitz-Stegun 7.1.26 erf approx, |eps| <= 1.5e-7.
__device__ __forceinline__ float laplacian_attn(float x) {
  float z  = (x - 0.70710678118654752f) * 0.79788456080286536f;
  float az = fabsf(z);
  float t  = __builtin_amdgcn_rcpf(fmaf(0.3275911f, az, 1.0f));
  float w  = fmaf(1.061405429f, t, -1.453152027f);
  w = fmaf(w, t, 1.421413741f);
  w = fmaf(w, t, -0.284496736f);
  w = fmaf(w, t, 0.254829592f);
  float P  = w * t;
  float E  = __expf(-z * z);
  float ea = fmaf(-P, E, 1.0f);            // erf(|z|)
  float er = copysignf(ea, z);
  return fmaf(0.5f, er, 0.5f);
}

// global->LDS DMA, 16B per lane.
__device__ __forceinline__ void gload16(const uint16_t* g, uint16_t* l) {
  __builtin_amdgcn_global_load_lds(
      (const __attribute__((address_space(1))) void*)g,
      (__attribute__((address_space(3))) void*)l, 16, 0, 0);
}

// counted-vmcnt barrier: wait until <=N of this wave's vmem ops outstanding
// (oldest-first), then block-sync. N=4 leaves the next stage in flight.
#define PIPE_BARRIER(cond4)                                          \
  do {                                                               \
    if (cond4) asm volatile("s_waitcnt vmcnt(4)" ::: "memory");      \
    else       asm volatile("s_waitcnt vmcnt(0)" ::: "memory");      \
    __builtin_amdgcn_s_barrier();                                    \
    __builtin_amdgcn_sched_barrier(0);                               \
  } while (0)

// ---- wave-private MTxNT (16-row units) GEMM on TILED operands -------------
// (reg-direct; used by k_gemm_sim where K is tiny)
template <int MT, int NT, int DEPTH>
__device__ __forceinline__ void wave_gemm_t(
    const uint16_t* __restrict__ A, int KBa, int rbA,
    const uint16_t* __restrict__ Bt, int KBb, int rbB,
    int nkb, f32x4 acc[MT][NT])
{
  const int lane = threadIdx.x & 63;

  const uint16_t* pa[MT];
  const uint16_t* pb[NT];
  #pragma unroll
  for (int mt = 0; mt < MT; mt++)
    pa[mt] = A + (size_t)(rbA + mt) * KBa * 512 + lane * 8;
  #pragma unroll
  for (int nt = 0; nt < NT; nt++)
    pb[nt] = Bt + (size_t)(rbB + nt) * KBb * 512 + lane * 8;

  #pragma unroll
  for (int mt = 0; mt < MT; mt++)
    #pragma unroll
    for (int nt = 0; nt < NT; nt++) {
      f32x4 z = {0.0f, 0.0f, 0.0f, 0.0f};
      acc[mt][nt] = z;
    }

  short8 fa0[MT], fb0[NT], fa1[MT], fb1[NT];

  auto loads = [&](short8 fa[MT], short8 fb[NT], int kb) {
    #pragma unroll
    for (int mt = 0; mt < MT; mt++)
      fa[mt] = *(const short8*)(pa[mt] + (size_t)kb * 512);
    #pragma unroll
    for (int nt = 0; nt < NT; nt++)
      fb[nt] = *(const short8*)(pb[nt] + (size_t)kb * 512);
  };
  auto mfmas = [&](short8 fa[MT], short8 fb[NT]) {
    #pragma unroll
    for (int mt = 0; mt < MT; mt++)
      #pragma unroll
      for (int nt = 0; nt < NT; nt++)
        acc[mt][nt] = __builtin_amdgcn_mfma_f32_16x16x32_bf16(
            fa[mt], fb[nt], acc[mt][nt], 0, 0, 0);
  };

  if constexpr (DEPTH == 2) {
    loads(fa0, fb0, 0);
    loads(fa1, fb1, 1);
    for (int kb = 2; kb < nkb; kb += 2) {
      mfmas(fa0, fb0);
      loads(fa0, fb0, kb);
      mfmas(fa1, fb1);
      loads(fa1, fb1, kb + 1);
    }
    mfmas(fa0, fb0);
    mfmas(fa1, fb1);
  } else {
    short8 fa2[MT], fb2[NT], fa3[MT], fb3[NT];
    loads(fa0, fb0, 0);
    loads(fa1, fb1, 1);
    loads(fa2, fb2, 2);
    loads(fa3, fb3, 3);
    for (int kb = 4; kb < nkb; kb += 4) {
      mfmas(fa0, fb0);
      loads(fa0, fb0, kb);
      mfmas(fa1, fb1);
      loads(fa1, fb1, kb + 1);
      mfmas(fa2, fb2);
      loads(fa2, fb2, kb + 2);
      mfmas(fa3, fb3);
      loads(fa3, fb3, kb + 3);
    }
    mfmas(fa0, fb0);
    mfmas(fa1, fb1);
    mfmas(fa2, fb2);
    mfmas(fa3, fb3);
  }
}

// ---- fused prep kernel -----------------------------------------------------
__global__ __launch_bounds__(256) void k_prep(
    const float* __restrict__ x, const float* __restrict__ wqk,
    const float* __restrict__ wv, const float* __restrict__ rel,
    uint16_t* __restrict__ xb, uint16_t* __restrict__ wT,
    float* __restrict__ bias_n)
{
  int blk = blockIdx.x;
  if (blk < 4096) {
    int t = blk * 256 + threadIdx.x;           // 0 .. 8192*128-1
    int i16 = t & 15, oct = (t >> 4) & 3, kb = (t >> 6) & 31, ib = t >> 11;
    const float* src = x + (size_t)(ib * 16 + i16) * DIM_ + kb * 32 + oct * 8;
    float4 a = *(const float4*)src;
    float4 b = *(const float4*)(src + 4);
    short8 o;
    o[0] = f32_to_bf16(a.x); o[1] = f32_to_bf16(a.y);
    o[2] = f32_to_bf16(a.z); o[3] = f32_to_bf16(a.w);
    o[4] = f32_to_bf16(b.x); o[5] = f32_to_bf16(b.y);
    o[6] = f32_to_bf16(b.z); o[7] = f32_to_bf16(b.w);
    *(short8*)(xb + (size_t)t * 8) = o;
  } else if (blk < 4672) {
    int t = (blk - 4096) * 256 + threadIdx.x;  // 0 .. 1152*128-1
    int n16 = t & 15, oct = (t >> 4) & 3, kb = (t >> 6) & 31, nb = t >> 11;
    int n = nb * 16 + n16;
    int k0 = kb * 32 + oct * 8;
    short8 o;
    if (n < DQK) {
      #pragma unroll
      for (int j = 0; j < 8; j++)
        o[j] = f32_to_bf16(wqk[(size_t)(k0 + j) * DQK + n]);
    } else {
      int nn = n - DQK;
      #pragma unroll
      for (int j = 0; j < 8; j++)
        o[j] = f32_to_bf16(wv[(size_t)(k0 + j) * DV + nn]);
    }
    *(short8*)(wT + (size_t)t * 8) = o;
  } else {
    for (int n = threadIdx.x; n < S_; n += 256) {
      int bucket;
      if (n < 16) {
        bucket = n;
      } else {
        float tt = logf((float)n * 0.0625f) / 2.0794415416798357f * 16.0f;
        int vl = 16 + (int)tt;
        bucket = vl < 31 ? vl : 31;
      }
      bias_n[n] = rel[bucket] * 11.313708498984761f;
    }
  }
}

// ---- GEMM kernels ----------------------------------------------------------

// fused projections, LDS-staged, depth-2 pipeline (3 bufs, BK=32, counted
// vmcnt barrier). 1-D grid 576, XCD-pinned. bx==0: q/k epilogue (SWAPPED
// operands -> packed 8B stores); bx>=1: v->vT.
__global__ __launch_bounds__(256, 3) void k_gemm_qkv(
    const uint16_t* __restrict__ xb, const uint16_t* __restrict__ wT,
    const float* __restrict__ bqk, const float* __restrict__ gamma,
    const float* __restrict__ beta, const float* __restrict__ bv,
    uint16_t* __restrict__ qb, uint16_t* __restrict__ kb,
    uint16_t* __restrict__ vT)
{
  int L = blockIdx.x;                    // 0..575
  int c = L & 7;
  int idx = L >> 3;                      // 0..71
  int by = c + 8 * (idx / 9);
  int bx = idx % 9;
  int lane = threadIdx.x & 63;
  int wave = threadIdx.x >> 6;
  int lane16 = lane & 15;
  int quad = lane >> 4;
  int wrow = (wave >> 1) * 64;
  int wcol = (wave & 1) * 64;

  __shared__ uint16_t sA[3][8 * 512];    // [buf][rbu*512]
  __shared__ uint16_t sB[3][8 * 512];

  const uint16_t *Ab, *Bb;
  if (bx == 0) { Ab = wT;                              Bb = xb + (size_t)by * 8 * 32 * 512; }
  else         { Ab = xb + (size_t)by * 8 * 32 * 512;  Bb = wT + (size_t)bx * 8 * 32 * 512; }

  const uint16_t* gp = (wave >> 1) ? Bb : Ab;
  int rb0 = (wave & 1) * 4;

  // wave stages rows rb0..rb0+3 of its panel for k-block kbi into buf b.
  // EXACTLY 4 vmem ops per stage (vmcnt accounting depends on this).
  auto stage = [&](int b, int kbi) {
    uint16_t* sp = (wave >> 1) ? sB[b] : sA[b];
    #pragma unroll
    for (int r = 0; r < 4; r++) {
      int rbu = rb0 + r;
      gload16(gp + ((size_t)rbu * 32 + kbi) * 512 + lane * 8,
              sp + rbu * 512);
    }
  };

  f32x4 acc[4][4];
  #pragma unroll
  for (int mt = 0; mt < 4; mt++)
    #pragma unroll
    for (int nt = 0; nt < 4; nt++) {
      f32x4 z = {0.0f, 0.0f, 0.0f, 0.0f};
      acc[mt][nt] = z;
    }

  stage(0, 0);
  stage(1, 1);
  for (int kbi = 0; kbi < 32; ++kbi) {
    PIPE_BARRIER(kbi + 1 < 32);          // stage(kbi) landed; kbi+1 in flight
    if (kbi + 2 < 32) stage((kbi + 2) % 3, kbi + 2);
    int cur = kbi % 3;
    short8 fa[4], fb[4];
    #pragma unroll
    for (int mt = 0; mt < 4; mt++)
      fa[mt] = *(const short8*)(sA[cur] + ((wave >> 1) * 4 + mt) * 512 + lane * 8);
    #pragma unroll
    for (int nt = 0; nt < 4; nt++)
      fb[nt] = *(const short8*)(sB[cur] + ((wave & 1) * 4 + nt) * 512 + lane * 8);
    #pragma unroll
    for (int mt = 0; mt < 4; mt++)
      #pragma unroll
      for (int nt = 0; nt < 4; nt++)
        acc[mt][nt] = __builtin_amdgcn_mfma_f32_16x16x32_bf16(
            fa[mt], fb[nt], acc[mt][nt], 0, 0, 0);
  }

  if (bx == 0) {
    int ibase = by * 128 + (wave & 1) * 64;
    int cbase = (wave >> 1) * 64;
    #pragma unroll
    for (int mt = 0; mt < 4; mt++) {
      int c0 = cbase + mt * 16 + quad * 4;
      float4 bb = *(const float4*)(bqk + c0);
      float4 g0 = *(const float4*)(gamma + c0);
      float4 g1 = *(const float4*)(gamma + DQK + c0);
      float4 e0 = *(const float4*)(beta + c0);
      float4 e1 = *(const float4*)(beta + DQK + c0);
      size_t coff = (size_t)(c0 >> 5) * 512 + ((c0 >> 3) & 3) * 128 + (c0 & 7);
      #pragma unroll
      for (int nt = 0; nt < 4; nt++) {
        int i = ibase + nt * 16 + lane16;
        float s0 = silu_f(acc[mt][nt][0] + bb.x);
        float s1 = silu_f(acc[mt][nt][1] + bb.y);
        float s2 = silu_f(acc[mt][nt][2] + bb.z);
        float s3 = silu_f(acc[mt][nt][3] + bb.w);
        uint2 pq, pk;
        pq.x = pack_bf16(fmaf(s0, g0.x, e0.x), fmaf(s1, g0.y, e0.y));
        pq.y = pack_bf16(fmaf(s2, g0.z, e0.z), fmaf(s3, g0.w, e0.w));
        pk.x = pack_bf16(fmaf(s0, g1.x, e1.x), fmaf(s1, g1.y, e1.y));
        pk.y = pack_bf16(fmaf(s2, g1.z, e1.z), fmaf(s3, g1.w, e1.w));
        size_t off = (size_t)(i >> 4) * 4 * 512 + (size_t)(i & 15) * 8 + coff;
        *(uint2*)(qb + off) = pq;
        *(uint2*)(kb + off) = pk;
      }
    }
  } else {
    int b = by >> 4;                               // batch (by*128 / 2048)
    uint16_t* vt = vT + (size_t)b * DV * S_;
    #pragma unroll
    for (int nt = 0; nt < 4; nt++) {
      int n = (bx - 1) * 128 + wcol + nt * 16 + lane16;   // 0..1023
      float bb = bv[n];
      #pragma unroll
      for (int mt = 0; mt < 4; mt++) {
        int j0l = (by & 15) * 128 + wrow + mt * 16 + quad * 4; // local seq
        uint16_t v0 = f32_to_bf16(silu_f(acc[mt][nt][0] + bb));
        uint16_t v1 = f32_to_bf16(silu_f(acc[mt][nt][1] + bb));
        uint16_t v2 = f32_to_bf16(silu_f(acc[mt][nt][2] + bb));
        uint16_t v3 = f32_to_bf16(silu_f(acc[mt][nt][3] + bb));
        size_t off = (size_t)((n >> 4) * 64 + (j0l >> 5)) * 512 +
                     ((j0l >> 3) & 3) * 128 + (n & 15) * 8 + (j0l & 7);
        uint2 pk;
        pk.x = (uint32_t)v0 | ((uint32_t)v1 << 16);
        pk.y = (uint32_t)v2 | ((uint32_t)v3 << 16);
        *(uint2*)(vt + off) = pk;
      }
    }
  }
}

// attn = laplacian(q@k^T/S + bias[i-j]) causal, TILED bf16 per batch.
// 64x64 tile per 128-thread block (2 waves); exact causal triangle grid.
// SWAPPED: A = kb rows (j), B = qb rows (i).  (exact R14 config)
__global__ __launch_bounds__(128, 4) void k_gemm_sim(
    const uint16_t* __restrict__ qb, const uint16_t* __restrict__ kb,
    const float* __restrict__ bias_n, uint16_t* __restrict__ attn)
{
  int b = blockIdx.x;                    // 0..527 triangular tile index
  int bt = blockIdx.y;                   // batch
  int it = (int)((sqrtf(8.0f * (float)b + 1.0f) - 1.0f) * 0.5f);
  while ((it + 1) * (it + 2) / 2 <= b) ++it;
  while (it * (it + 1) / 2 > b) --it;
  int jt = b - it * (it + 1) / 2;        // 0..it

  int lane = threadIdx.x & 63;
  int wave = threadIdx.x >> 6;           // 0..1 (i-halves of the 64-row tile)
  int lane16 = lane & 15;
  int quad = lane >> 4;

  f32x4 acc[4][2];
  wave_gemm_t<4,2,2>(kb, 4, bt * 128 + jt * 4,
                     qb, 4, bt * 128 + it * 4 + wave * 2,
                     4, acc);

  uint16_t* ab = attn + (size_t)bt * S_ * S_;
  int ibase = it * 64 + wave * 32;
  int jbase = jt * 64;
  #pragma unroll
  for (int nt = 0; nt < 2; nt++) {
    int i = ibase + nt * 16 + lane16;
    size_t irow = (size_t)(i >> 4) * 64 * 512 + (size_t)(i & 15) * 8;
    #pragma unroll
    for (int mt = 0; mt < 4; mt++) {
      int j0 = jbase + mt * 16 + quad * 4;
      float v[4];
      #pragma unroll
      for (int r = 0; r < 4; r++) {
        int j = j0 + r;
        float aval = 0.0f;
        if (j <= i) {
          float sim = acc[mt][nt][r] * (1.0f / 2048.0f) + bias_n[i - j];
          aval = laplacian_attn(sim);
        }
        v[r] = aval;
      }
      uint2 pk;
      pk.x = pack_bf16(v[0], v[1]);
      pk.y = pack_bf16(v[2], v[3]);
      size_t off = irow + (size_t)(j0 >> 5) * 512 + ((j0 >> 3) & 3) * 128 +
                   (j0 & 7);
      *(uint2*)(ab + off) = pk;
    }
  }
}

// out = attn @ v, fp32 out, LDS-staged, depth-2 pipeline (3 bufs, BK=32,
// counted vmcnt barrier). 1-D grid 512: XCD c serves ONE bt (c>>1);
// nx=(c&1)*4+(m&3); it=15-(m>>2) (LPT desc). SWAPPED operands: A=vT (n rows,
// sA), B=attn (i rows, sB) -> float4 epilogue stores.
__global__ __launch_bounds__(256, 3) void k_gemm_out(
    const uint16_t* __restrict__ attn, const uint16_t* __restrict__ vT,
    float* __restrict__ out)
{
  int L = blockIdx.x;                    // 0..511
  int c = L & 7, m = L >> 3;             // c: XCD residue, m: 0..63
  int bt = c >> 1;                       // one batch per XCD pair-residue
  int nx = (c & 1) * 4 + (m & 3);        // 0..7
  int it = 15 - (m >> 2);                // descending -> LPT
  int nkb = 4 * it + 4;                  // causal K bound (32-wide k-blocks)
  int lane = threadIdx.x & 63;
  int wave = threadIdx.x >> 6;
  int lane16 = lane & 15;
  int quad = lane >> 4;
  int wrow = (wave >> 1) * 64;
  int wcol = (wave & 1) * 64;

  __shared__ uint16_t sA[3][8 * 512];
  __shared__ uint16_t sB[3][8 * 512];

  const uint16_t* Ab = vT + (size_t)bt * DV * S_ + (size_t)nx * 8 * 64 * 512;
  const uint16_t* Bb = attn + (size_t)bt * S_ * S_ + (size_t)it * 8 * 64 * 512;

  const uint16_t* gp = (wave >> 1) ? Bb : Ab;
  int rb0 = (wave & 1) * 4;

  auto stage = [&](int b, int kbi) {
    uint16_t* sp = (wave >> 1) ? sB[b] : sA[b];
    #pragma unroll
    for (int r = 0; r < 4; r++) {
      int rbu = rb0 + r;
      gload16(gp + ((size_t)rbu * 64 + kbi) * 512 + lane * 8,
              sp + rbu * 512);
    }
  };

  f32x4 acc[4][4];
  #pragma unroll
  for (int mt = 0; mt < 4; mt++)
    #pragma unroll
    for (int nt = 0; nt < 4; nt++) {
      f32x4 z = {0.0f, 0.0f, 0.0f, 0.0f};
      acc[mt][nt] = z;
    }

  stage(0, 0);
  stage(1, 1);                           // nkb >= 4 always
  for (int kbi = 0; kbi < nkb; ++kbi) {
    PIPE_BARRIER(kbi + 1 < nkb);
    if (kbi + 2 < nkb) stage((kbi + 2) % 3, kbi + 2);
    int cur = kbi % 3;
    short8 fa[4], fb[4];
    #pragma unroll
    for (int mt = 0; mt < 4; mt++)
      fa[mt] = *(const short8*)(sA[cur] + ((wave & 1) * 4 + mt) * 512 + lane * 8);
    #pragma unroll
    for (int nt = 0; nt < 4; nt++)
      fb[nt] = *(const short8*)(sB[cur] + ((wave >> 1) * 4 + nt) * 512 + lane * 8);
    #pragma unroll
    for (int mt = 0; mt < 4; mt++)
      #pragma unroll
      for (int nt = 0; nt < 4; nt++)
        acc[mt][nt] = __builtin_amdgcn_mfma_f32_16x16x32_bf16(
            fa[mt], fb[nt], acc[mt][nt], 0, 0, 0);
  }

  // acc[mt][nt][r]: n = nx*128 + wcol + mt*16 + quad*4 + r
  //                 i = it*128 + wrow + nt*16 + lane16
  float* ob = out + ((size_t)bt * S_ + it * 128 + wrow) * DV + nx * 128 + wcol;
  #pragma unroll
  for (int nt = 0; nt < 4; nt++) {
    int i = nt * 16 + lane16;
    #pragma unroll
    for (int mt = 0; mt < 4; mt++) {
      int n = mt * 16 + quad * 4;
      *(float4*)(ob + (size_t)i * DV + n) = *(float4*)&acc[mt][nt];
    }
  }
}

// ---------------------------------------------------------------------------

extern "C" void kernel_launch(void* const* d_in, const int* in_sizes, int n_in,
                              void* d_out, int out_size, void* d_ws, size_t ws_size,
                              hipStream_t stream)
{
  const float* x     = (const float*)d_in[0];
  const float* wqk   = (const float*)d_in[1];
  const float* bqk   = (const float*)d_in[2];
  const float* gamma = (const float*)d_in[3];
  const float* beta  = (const float*)d_in[4];
  const float* wv    = (const float*)d_in[5];
  const float* bv    = (const float*)d_in[6];
  const float* rel   = (const float*)d_in[7];
  float* out = (float*)d_out;

  char* ws = (char*)d_ws;
  size_t off = 0;
  uint16_t* xb     = (uint16_t*)(ws + off); off += (size_t)B_ * S_ * DIM_ * 2;  // 16 MB
  uint16_t* wT     = (uint16_t*)(ws + off); off += (size_t)NQV * DIM_ * 2;      // 2.25 MB
  uint16_t* qb     = (uint16_t*)(ws + off); off += (size_t)B_ * S_ * DQK * 2;   // 2 MB
  uint16_t* kb     = (uint16_t*)(ws + off); off += (size_t)B_ * S_ * DQK * 2;   // 2 MB
  uint16_t* vT     = (uint16_t*)(ws + off); off += (size_t)B_ * DV * S_ * 2;    // 16 MB
  uint16_t* attn   = (uint16_t*)(ws + off); off += (size_t)B_ * S_ * S_ * 2;    // 32 MB
  float*    bias_n = (float*)(ws + off);    off += (size_t)S_ * 4;              // 8 KB

  k_prep<<<dim3(4673), dim3(256), 0, stream>>>(x, wqk, wv, rel, xb, wT, bias_n);

  k_gemm_qkv<<<dim3(576), dim3(256), 0, stream>>>(
      xb, wT, bqk, gamma, beta, bv, qb, kb, vT);
  k_gemm_sim<<<dim3(528, B_), dim3(128), 0, stream>>>(
      qb, kb, bias_n, attn);
  k_gemm_out<<<dim3(512), dim3(256), 0, stream>>>(
      attn, vT, out);
}

// Round 14
// 162.761 us; speedup vs baseline: 1.0655x; 1.0309x over previous
//
#include <hip/hip_runtime.h>
#include <stdint.h>

// ---------------------------------------------------------------------------
// SingleHeadedAttention (Mega-style, laplacian attn fn, causal, T5 rel bias)
// B=4, S=2048, DIM=1024, DQK=128, DV=1024.  fp32 in/out, bf16 MFMA internals.
// R22: R21 (167.8us best) + sim DEPTH2 -> DEPTH4: all 24 fragment loads
//   (4 kb x (4 A + 2 B)) issued in ONE batch -> single L2-latency exposure
//   per 64x64 tile (was two). Same mechanism as R19/R21's wins, applied to
//   the last untouched kernel (~26-32us for 2.3 GFLOP, worst efficiency).
//   R16's k_simv ran this variant refcheck'd at 52 VGPR. qkv/out unchanged.
// R21: depth-2 staging pipeline in qkv/out (3 LDS bufs, counted vmcnt(4)
//   barrier; loads cross barriers). R19: 2-phase dbuf (BK=32). R15 lesson:
//   NO cross-block deps in-launch. R14: LDS-staged bodies (global_load_lds
//   w=16). R13: XCD-pinned grids, fused prep. R12: swapped epilogues, LPT.
// R11: sim 32x64 wave tiles, triangle grid. R10: branchless erf, swapped QKT.
//   TILED: element (row,k) of [R][K] at
//     ((row>>4)*(K>>5) + (k>>5))*512 + ((k>>3)&3)*128 + (row&15)*8 + (k&7).
// ---------------------------------------------------------------------------

#define B_   4
#define S_   2048
#define DIM_ 1024
#define DQK  128
#define DV   1024
#define NQV  1152

typedef __attribute__((ext_vector_type(8))) short short8;   // 8 bf16
typedef __attribute__((ext_vector_type(4))) float f32x4;    // MFMA C/D

__device__ __forceinline__ uint16_t f32_to_bf16(float f) {
  uint32_t u = __float_as_uint(f);
  u += 0x7FFFu + ((u >> 16) & 1u);          // round-to-nearest-even
  return (uint16_t)(u >> 16);
}

__device__ __forceinline__ uint32_t pack_bf16(float a, float b) {
  return (uint32_t)f32_to_bf16(a) | ((uint32_t)f32_to_bf16(b) << 16);
}

__device__ __forceinline__ float silu_f(float x) {
  return x * __builtin_amdgcn_rcpf(1.0f + __expf(-x));
}

// 0.5*(1+erf((x-mu)/(std*sqrt2))), mu=sqrt(0.5), std=sqrt(pi/4).
// Branchless Abramowitz-Stegun 7.1.26 erf approx, |eps| <= 1.5e-7.
__device__ __forceinline__ float laplacian_attn(float x) {
  float z  = (x - 0.70710678118654752f) * 0.79788456080286536f;
  float az = fabsf(z);
  float t  = __builtin_amdgcn_rcpf(fmaf(0.3275911f, az, 1.0f));
  float w  = fmaf(1.061405429f, t, -1.453152027f);
  w = fmaf(w, t, 1.421413741f);
  w = fmaf(w, t, -0.284496736f);
  w = fmaf(w, t, 0.254829592f);
  float P  = w * t;
  float E  = __expf(-z * z);
  float ea = fmaf(-P, E, 1.0f);            // erf(|z|)
  float er = copysignf(ea, z);
  return fmaf(0.5f, er, 0.5f);
}

// global->LDS DMA, 16B per lane.
__device__ __forceinline__ void gload16(const uint16_t* g, uint16_t* l) {
  __builtin_amdgcn_global_load_lds(
      (const __attribute__((address_space(1))) void*)g,
      (__attribute__((address_space(3))) void*)l, 16, 0, 0);
}

// counted-vmcnt barrier: wait until <=N of this wave's vmem ops outstanding
// (oldest-first), then block-sync. N=4 leaves the next stage in flight.
#define PIPE_BARRIER(cond4)                                          \
  do {                                                               \
    if (cond4) asm volatile("s_waitcnt vmcnt(4)" ::: "memory");      \
    else       asm volatile("s_waitcnt vmcnt(0)" ::: "memory");      \
    __builtin_amdgcn_s_barrier();                                    \
    __builtin_amdgcn_sched_barrier(0);                               \
  } while (0)

// ---- wave-private MTxNT (16-row units) GEMM on TILED operands -------------
// (reg-direct; used by k_gemm_sim where K is tiny)
template <int MT, int NT, int DEPTH>
__device__ __forceinline__ void wave_gemm_t(
    const uint16_t* __restrict__ A, int KBa, int rbA,
    const uint16_t* __restrict__ Bt, int KBb, int rbB,
    int nkb, f32x4 acc[MT][NT])
{
  const int lane = threadIdx.x & 63;

  const uint16_t* pa[MT];
  const uint16_t* pb[NT];
  #pragma unroll
  for (int mt = 0; mt < MT; mt++)
    pa[mt] = A + (size_t)(rbA + mt) * KBa * 512 + lane * 8;
  #pragma unroll
  for (int nt = 0; nt < NT; nt++)
    pb[nt] = Bt + (size_t)(rbB + nt) * KBb * 512 + lane * 8;

  #pragma unroll
  for (int mt = 0; mt < MT; mt++)
    #pragma unroll
    for (int nt = 0; nt < NT; nt++) {
      f32x4 z = {0.0f, 0.0f, 0.0f, 0.0f};
      acc[mt][nt] = z;
    }

  short8 fa0[MT], fb0[NT], fa1[MT], fb1[NT];

  auto loads = [&](short8 fa[MT], short8 fb[NT], int kb) {
    #pragma unroll
    for (int mt = 0; mt < MT; mt++)
      fa[mt] = *(const short8*)(pa[mt] + (size_t)kb * 512);
    #pragma unroll
    for (int nt = 0; nt < NT; nt++)
      fb[nt] = *(const short8*)(pb[nt] + (size_t)kb * 512);
  };
  auto mfmas = [&](short8 fa[MT], short8 fb[NT]) {
    #pragma unroll
    for (int mt = 0; mt < MT; mt++)
      #pragma unroll
      for (int nt = 0; nt < NT; nt++)
        acc[mt][nt] = __builtin_amdgcn_mfma_f32_16x16x32_bf16(
            fa[mt], fb[nt], acc[mt][nt], 0, 0, 0);
  };

  if constexpr (DEPTH == 2) {
    loads(fa0, fb0, 0);
    loads(fa1, fb1, 1);
    for (int kb = 2; kb < nkb; kb += 2) {
      mfmas(fa0, fb0);
      loads(fa0, fb0, kb);
      mfmas(fa1, fb1);
      loads(fa1, fb1, kb + 1);
    }
    mfmas(fa0, fb0);
    mfmas(fa1, fb1);
  } else {
    short8 fa2[MT], fb2[NT], fa3[MT], fb3[NT];
    loads(fa0, fb0, 0);
    loads(fa1, fb1, 1);
    loads(fa2, fb2, 2);
    loads(fa3, fb3, 3);
    for (int kb = 4; kb < nkb; kb += 4) {
      mfmas(fa0, fb0);
      loads(fa0, fb0, kb);
      mfmas(fa1, fb1);
      loads(fa1, fb1, kb + 1);
      mfmas(fa2, fb2);
      loads(fa2, fb2, kb + 2);
      mfmas(fa3, fb3);
      loads(fa3, fb3, kb + 3);
    }
    mfmas(fa0, fb0);
    mfmas(fa1, fb1);
    mfmas(fa2, fb2);
    mfmas(fa3, fb3);
  }
}

// ---- fused prep kernel -----------------------------------------------------
__global__ __launch_bounds__(256) void k_prep(
    const float* __restrict__ x, const float* __restrict__ wqk,
    const float* __restrict__ wv, const float* __restrict__ rel,
    uint16_t* __restrict__ xb, uint16_t* __restrict__ wT,
    float* __restrict__ bias_n)
{
  int blk = blockIdx.x;
  if (blk < 4096) {
    int t = blk * 256 + threadIdx.x;           // 0 .. 8192*128-1
    int i16 = t & 15, oct = (t >> 4) & 3, kb = (t >> 6) & 31, ib = t >> 11;
    const float* src = x + (size_t)(ib * 16 + i16) * DIM_ + kb * 32 + oct * 8;
    float4 a = *(const float4*)src;
    float4 b = *(const float4*)(src + 4);
    short8 o;
    o[0] = f32_to_bf16(a.x); o[1] = f32_to_bf16(a.y);
    o[2] = f32_to_bf16(a.z); o[3] = f32_to_bf16(a.w);
    o[4] = f32_to_bf16(b.x); o[5] = f32_to_bf16(b.y);
    o[6] = f32_to_bf16(b.z); o[7] = f32_to_bf16(b.w);
    *(short8*)(xb + (size_t)t * 8) = o;
  } else if (blk < 4672) {
    int t = (blk - 4096) * 256 + threadIdx.x;  // 0 .. 1152*128-1
    int n16 = t & 15, oct = (t >> 4) & 3, kb = (t >> 6) & 31, nb = t >> 11;
    int n = nb * 16 + n16;
    int k0 = kb * 32 + oct * 8;
    short8 o;
    if (n < DQK) {
      #pragma unroll
      for (int j = 0; j < 8; j++)
        o[j] = f32_to_bf16(wqk[(size_t)(k0 + j) * DQK + n]);
    } else {
      int nn = n - DQK;
      #pragma unroll
      for (int j = 0; j < 8; j++)
        o[j] = f32_to_bf16(wv[(size_t)(k0 + j) * DV + nn]);
    }
    *(short8*)(wT + (size_t)t * 8) = o;
  } else {
    for (int n = threadIdx.x; n < S_; n += 256) {
      int bucket;
      if (n < 16) {
        bucket = n;
      } else {
        float tt = logf((float)n * 0.0625f) / 2.0794415416798357f * 16.0f;
        int vl = 16 + (int)tt;
        bucket = vl < 31 ? vl : 31;
      }
      bias_n[n] = rel[bucket] * 11.313708498984761f;
    }
  }
}

// ---- GEMM kernels ----------------------------------------------------------

// fused projections, LDS-staged, depth-2 pipeline (3 bufs, BK=32, counted
// vmcnt barrier). 1-D grid 576, XCD-pinned. bx==0: q/k epilogue (SWAPPED
// operands -> packed 8B stores); bx>=1: v->vT.
__global__ __launch_bounds__(256, 3) void k_gemm_qkv(
    const uint16_t* __restrict__ xb, const uint16_t* __restrict__ wT,
    const float* __restrict__ bqk, const float* __restrict__ gamma,
    const float* __restrict__ beta, const float* __restrict__ bv,
    uint16_t* __restrict__ qb, uint16_t* __restrict__ kb,
    uint16_t* __restrict__ vT)
{
  int L = blockIdx.x;                    // 0..575
  int c = L & 7;
  int idx = L >> 3;                      // 0..71
  int by = c + 8 * (idx / 9);
  int bx = idx % 9;
  int lane = threadIdx.x & 63;
  int wave = threadIdx.x >> 6;
  int lane16 = lane & 15;
  int quad = lane >> 4;
  int wrow = (wave >> 1) * 64;
  int wcol = (wave & 1) * 64;

  __shared__ uint16_t sA[3][8 * 512];    // [buf][rbu*512]
  __shared__ uint16_t sB[3][8 * 512];

  const uint16_t *Ab, *Bb;
  if (bx == 0) { Ab = wT;                              Bb = xb + (size_t)by * 8 * 32 * 512; }
  else         { Ab = xb + (size_t)by * 8 * 32 * 512;  Bb = wT + (size_t)bx * 8 * 32 * 512; }

  const uint16_t* gp = (wave >> 1) ? Bb : Ab;
  int rb0 = (wave & 1) * 4;

  // wave stages rows rb0..rb0+3 of its panel for k-block kbi into buf b.
  // EXACTLY 4 vmem ops per stage (vmcnt accounting depends on this).
  auto stage = [&](int b, int kbi) {
    uint16_t* sp = (wave >> 1) ? sB[b] : sA[b];
    #pragma unroll
    for (int r = 0; r < 4; r++) {
      int rbu = rb0 + r;
      gload16(gp + ((size_t)rbu * 32 + kbi) * 512 + lane * 8,
              sp + rbu * 512);
    }
  };

  f32x4 acc[4][4];
  #pragma unroll
  for (int mt = 0; mt < 4; mt++)
    #pragma unroll
    for (int nt = 0; nt < 4; nt++) {
      f32x4 z = {0.0f, 0.0f, 0.0f, 0.0f};
      acc[mt][nt] = z;
    }

  stage(0, 0);
  stage(1, 1);
  for (int kbi = 0; kbi < 32; ++kbi) {
    PIPE_BARRIER(kbi + 1 < 32);          // stage(kbi) landed; kbi+1 in flight
    if (kbi + 2 < 32) stage((kbi + 2) % 3, kbi + 2);
    int cur = kbi % 3;
    short8 fa[4], fb[4];
    #pragma unroll
    for (int mt = 0; mt < 4; mt++)
      fa[mt] = *(const short8*)(sA[cur] + ((wave >> 1) * 4 + mt) * 512 + lane * 8);
    #pragma unroll
    for (int nt = 0; nt < 4; nt++)
      fb[nt] = *(const short8*)(sB[cur] + ((wave & 1) * 4 + nt) * 512 + lane * 8);
    #pragma unroll
    for (int mt = 0; mt < 4; mt++)
      #pragma unroll
      for (int nt = 0; nt < 4; nt++)
        acc[mt][nt] = __builtin_amdgcn_mfma_f32_16x16x32_bf16(
            fa[mt], fb[nt], acc[mt][nt], 0, 0, 0);
  }

  if (bx == 0) {
    int ibase = by * 128 + (wave & 1) * 64;
    int cbase = (wave >> 1) * 64;
    #pragma unroll
    for (int mt = 0; mt < 4; mt++) {
      int c0 = cbase + mt * 16 + quad * 4;
      float4 bb = *(const float4*)(bqk + c0);
      float4 g0 = *(const float4*)(gamma + c0);
      float4 g1 = *(const float4*)(gamma + DQK + c0);
      float4 e0 = *(const float4*)(beta + c0);
      float4 e1 = *(const float4*)(beta + DQK + c0);
      size_t coff = (size_t)(c0 >> 5) * 512 + ((c0 >> 3) & 3) * 128 + (c0 & 7);
      #pragma unroll
      for (int nt = 0; nt < 4; nt++) {
        int i = ibase + nt * 16 + lane16;
        float s0 = silu_f(acc[mt][nt][0] + bb.x);
        float s1 = silu_f(acc[mt][nt][1] + bb.y);
        float s2 = silu_f(acc[mt][nt][2] + bb.z);
        float s3 = silu_f(acc[mt][nt][3] + bb.w);
        uint2 pq, pk;
        pq.x = pack_bf16(fmaf(s0, g0.x, e0.x), fmaf(s1, g0.y, e0.y));
        pq.y = pack_bf16(fmaf(s2, g0.z, e0.z), fmaf(s3, g0.w, e0.w));
        pk.x = pack_bf16(fmaf(s0, g1.x, e1.x), fmaf(s1, g1.y, e1.y));
        pk.y = pack_bf16(fmaf(s2, g1.z, e1.z), fmaf(s3, g1.w, e1.w));
        size_t off = (size_t)(i >> 4) * 4 * 512 + (size_t)(i & 15) * 8 + coff;
        *(uint2*)(qb + off) = pq;
        *(uint2*)(kb + off) = pk;
      }
    }
  } else {
    int b = by >> 4;                               // batch (by*128 / 2048)
    uint16_t* vt = vT + (size_t)b * DV * S_;
    #pragma unroll
    for (int nt = 0; nt < 4; nt++) {
      int n = (bx - 1) * 128 + wcol + nt * 16 + lane16;   // 0..1023
      float bb = bv[n];
      #pragma unroll
      for (int mt = 0; mt < 4; mt++) {
        int j0l = (by & 15) * 128 + wrow + mt * 16 + quad * 4; // local seq
        uint16_t v0 = f32_to_bf16(silu_f(acc[mt][nt][0] + bb));
        uint16_t v1 = f32_to_bf16(silu_f(acc[mt][nt][1] + bb));
        uint16_t v2 = f32_to_bf16(silu_f(acc[mt][nt][2] + bb));
        uint16_t v3 = f32_to_bf16(silu_f(acc[mt][nt][3] + bb));
        size_t off = (size_t)((n >> 4) * 64 + (j0l >> 5)) * 512 +
                     ((j0l >> 3) & 3) * 128 + (n & 15) * 8 + (j0l & 7);
        uint2 pk;
        pk.x = (uint32_t)v0 | ((uint32_t)v1 << 16);
        pk.y = (uint32_t)v2 | ((uint32_t)v3 << 16);
        *(uint2*)(vt + off) = pk;
      }
    }
  }
}

// attn = laplacian(q@k^T/S + bias[i-j]) causal, TILED bf16 per batch.
// 64x64 tile per 128-thread block (2 waves); exact causal triangle grid.
// SWAPPED: A = kb rows (j), B = qb rows (i). R22: DEPTH4 -> all 24 fragment
// loads issued in one batch = single L2-latency exposure per tile.
__global__ __launch_bounds__(128, 4) void k_gemm_sim(
    const uint16_t* __restrict__ qb, const uint16_t* __restrict__ kb,
    const float* __restrict__ bias_n, uint16_t* __restrict__ attn)
{
  int b = blockIdx.x;                    // 0..527 triangular tile index
  int bt = blockIdx.y;                   // batch
  int it = (int)((sqrtf(8.0f * (float)b + 1.0f) - 1.0f) * 0.5f);
  while ((it + 1) * (it + 2) / 2 <= b) ++it;
  while (it * (it + 1) / 2 > b) --it;
  int jt = b - it * (it + 1) / 2;        // 0..it

  int lane = threadIdx.x & 63;
  int wave = threadIdx.x >> 6;           // 0..1 (i-halves of the 64-row tile)
  int lane16 = lane & 15;
  int quad = lane >> 4;

  f32x4 acc[4][2];
  wave_gemm_t<4,2,4>(kb, 4, bt * 128 + jt * 4,
                     qb, 4, bt * 128 + it * 4 + wave * 2,
                     4, acc);

  uint16_t* ab = attn + (size_t)bt * S_ * S_;
  int ibase = it * 64 + wave * 32;
  int jbase = jt * 64;
  #pragma unroll
  for (int nt = 0; nt < 2; nt++) {
    int i = ibase + nt * 16 + lane16;
    size_t irow = (size_t)(i >> 4) * 64 * 512 + (size_t)(i & 15) * 8;
    #pragma unroll
    for (int mt = 0; mt < 4; mt++) {
      int j0 = jbase + mt * 16 + quad * 4;
      float v[4];
      #pragma unroll
      for (int r = 0; r < 4; r++) {
        int j = j0 + r;
        float aval = 0.0f;
        if (j <= i) {
          float sim = acc[mt][nt][r] * (1.0f / 2048.0f) + bias_n[i - j];
          aval = laplacian_attn(sim);
        }
        v[r] = aval;
      }
      uint2 pk;
      pk.x = pack_bf16(v[0], v[1]);
      pk.y = pack_bf16(v[2], v[3]);
      size_t off = irow + (size_t)(j0 >> 5) * 512 + ((j0 >> 3) & 3) * 128 +
                   (j0 & 7);
      *(uint2*)(ab + off) = pk;
    }
  }
}

// out = attn @ v, fp32 out, LDS-staged, depth-2 pipeline (3 bufs, BK=32,
// counted vmcnt barrier). 1-D grid 512: XCD c serves ONE bt (c>>1);
// nx=(c&1)*4+(m&3); it=15-(m>>2) (LPT desc). SWAPPED operands: A=vT (n rows,
// sA), B=attn (i rows, sB) -> float4 epilogue stores.
__global__ __launch_bounds__(256, 3) void k_gemm_out(
    const uint16_t* __restrict__ attn, const uint16_t* __restrict__ vT,
    float* __restrict__ out)
{
  int L = blockIdx.x;                    // 0..511
  int c = L & 7, m = L >> 3;             // c: XCD residue, m: 0..63
  int bt = c >> 1;                       // one batch per XCD pair-residue
  int nx = (c & 1) * 4 + (m & 3);        // 0..7
  int it = 15 - (m >> 2);                // descending -> LPT
  int nkb = 4 * it + 4;                  // causal K bound (32-wide k-blocks)
  int lane = threadIdx.x & 63;
  int wave = threadIdx.x >> 6;
  int lane16 = lane & 15;
  int quad = lane >> 4;
  int wrow = (wave >> 1) * 64;
  int wcol = (wave & 1) * 64;

  __shared__ uint16_t sA[3][8 * 512];
  __shared__ uint16_t sB[3][8 * 512];

  const uint16_t* Ab = vT + (size_t)bt * DV * S_ + (size_t)nx * 8 * 64 * 512;
  const uint16_t* Bb = attn + (size_t)bt * S_ * S_ + (size_t)it * 8 * 64 * 512;

  const uint16_t* gp = (wave >> 1) ? Bb : Ab;
  int rb0 = (wave & 1) * 4;

  auto stage = [&](int b, int kbi) {
    uint16_t* sp = (wave >> 1) ? sB[b] : sA[b];
    #pragma unroll
    for (int r = 0; r < 4; r++) {
      int rbu = rb0 + r;
      gload16(gp + ((size_t)rbu * 64 + kbi) * 512 + lane * 8,
              sp + rbu * 512);
    }
  };

  f32x4 acc[4][4];
  #pragma unroll
  for (int mt = 0; mt < 4; mt++)
    #pragma unroll
    for (int nt = 0; nt < 4; nt++) {
      f32x4 z = {0.0f, 0.0f, 0.0f, 0.0f};
      acc[mt][nt] = z;
    }

  stage(0, 0);
  stage(1, 1);                           // nkb >= 4 always
  for (int kbi = 0; kbi < nkb; ++kbi) {
    PIPE_BARRIER(kbi + 1 < nkb);
    if (kbi + 2 < nkb) stage((kbi + 2) % 3, kbi + 2);
    int cur = kbi % 3;
    short8 fa[4], fb[4];
    #pragma unroll
    for (int mt = 0; mt < 4; mt++)
      fa[mt] = *(const short8*)(sA[cur] + ((wave & 1) * 4 + mt) * 512 + lane * 8);
    #pragma unroll
    for (int nt = 0; nt < 4; nt++)
      fb[nt] = *(const short8*)(sB[cur] + ((wave >> 1) * 4 + nt) * 512 + lane * 8);
    #pragma unroll
    for (int mt = 0; mt < 4; mt++)
      #pragma unroll
      for (int nt = 0; nt < 4; nt++)
        acc[mt][nt] = __builtin_amdgcn_mfma_f32_16x16x32_bf16(
            fa[mt], fb[nt], acc[mt][nt], 0, 0, 0);
  }

  // acc[mt][nt][r]: n = nx*128 + wcol + mt*16 + quad*4 + r
  //                 i = it*128 + wrow + nt*16 + lane16
  float* ob = out + ((size_t)bt * S_ + it * 128 + wrow) * DV + nx * 128 + wcol;
  #pragma unroll
  for (int nt = 0; nt < 4; nt++) {
    int i = nt * 16 + lane16;
    #pragma unroll
    for (int mt = 0; mt < 4; mt++) {
      int n = mt * 16 + quad * 4;
      *(float4*)(ob + (size_t)i * DV + n) = *(float4*)&acc[mt][nt];
    }
  }
}

// ---------------------------------------------------------------------------

extern "C" void kernel_launch(void* const* d_in, const int* in_sizes, int n_in,
                              void* d_out, int out_size, void* d_ws, size_t ws_size,
                              hipStream_t stream)
{
  const float* x     = (const float*)d_in[0];
  const float* wqk   = (const float*)d_in[1];
  const float* bqk   = (const float*)d_in[2];
  const float* gamma = (const float*)d_in[3];
  const float* beta  = (const float*)d_in[4];
  const float* wv    = (const float*)d_in[5];
  const float* bv    = (const float*)d_in[6];
  const float* rel   = (const float*)d_in[7];
  float* out = (float*)d_out;

  char* ws = (char*)d_ws;
  size_t off = 0;
  uint16_t* xb     = (uint16_t*)(ws + off); off += (size_t)B_ * S_ * DIM_ * 2;  // 16 MB
  uint16_t* wT     = (uint16_t*)(ws + off); off += (size_t)NQV * DIM_ * 2;      // 2.25 MB
  uint16_t* qb     = (uint16_t*)(ws + off); off += (size_t)B_ * S_ * DQK * 2;   // 2 MB
  uint16_t* kb     = (uint16_t*)(ws + off); off += (size_t)B_ * S_ * DQK * 2;   // 2 MB
  uint16_t* vT     = (uint16_t*)(ws + off); off += (size_t)B_ * DV * S_ * 2;    // 16 MB
  uint16_t* attn   = (uint16_t*)(ws + off); off += (size_t)B_ * S_ * S_ * 2;    // 32 MB
  float*    bias_n = (float*)(ws + off);    off += (size_t)S_ * 4;              // 8 KB

  k_prep<<<dim3(4673), dim3(256), 0, stream>>>(x, wqk, wv, rel, xb, wT, bias_n);

  k_gemm_qkv<<<dim3(576), dim3(256), 0, stream>>>(
      xb, wT, bqk, gamma, beta, bv, qb, kb, vT);
  k_gemm_sim<<<dim3(528, B_), dim3(128), 0, stream>>>(
      qb, kb, bias_n, attn);
  k_gemm_out<<<dim3(512), dim3(256), 0, stream>>>(
      attn, vT, out);
}